// Round 6
// baseline (991.380 us; speedup 1.0000x reference)
//
#include <hip/hip_runtime.h>

// ============================================================================
// ProteinLigandGNN: 2x GCNConv (protein), 2x GCNConv (ligand), mean-pool,
// FC + 3 heads.
//
// GCNConv: out = D^-1/2 (A+I) D^-1/2 (X W) + b  ==  (D^-1/2 (A+I) D^-1/2 X) W + b
// Aggregate FIRST (narrow feature space when possible), then transform.
// R3: protein h1 bf16 (halves layer-2 gather bytes); fused P+L launches.
// R4: layer-2 transform via MFMA bf16; agg2/W2 bf16.
// R5: scatter -> 2-pass bucketed (was 120us: 110MB WRITE for 6.6MB payload,
//     cross-XCD line sharing). agg2 -> 4 edges/wave, 16B/lane uint4 gather
//     (was 1 edge/wave at 4B/lane, latency-bound at 1.8TB/s); dinv[src]
//     folded into stored h1' table (no weight broadcast); ligand h1 bf16.
// ============================================================================

typedef unsigned short ushort_t;
typedef short bf16x8 __attribute__((ext_vector_type(8)));
typedef float f32x4 __attribute__((ext_vector_type(4)));

#define SCAN_CHUNK 2048
#define BSHIFT 8   // 256 dst nodes per scatter bucket

static __device__ inline ushort_t f2bf(float f) {  // RNE f32->bf16
  unsigned u = __float_as_uint(f);
  unsigned r = (u + 0x7FFFu + ((u >> 16) & 1u)) >> 16;
  return (ushort_t)r;
}
static __device__ inline float bf2f(ushort_t b) {
  return __uint_as_float((unsigned)b << 16);
}
static __device__ inline unsigned pack2bf(float lo, float hi) {
  return (unsigned)f2bf(lo) | ((unsigned)f2bf(hi) << 16);
}

// ---------------- fused degree count (both graphs) ----------------
__global__ void count_deg2_kernel(const int* __restrict__ dstP, int Ep, int* __restrict__ degP,
                                  const int* __restrict__ dstL, int El, int* __restrict__ degL) {
  int e = blockIdx.x * blockDim.x + threadIdx.x;
  if (e < Ep) atomicAdd(&degP[dstP[e]], 1);
  else if (e < Ep + El) atomicAdd(&degL[dstL[e - Ep]], 1);
}

// ---------------- fused per-node prep: dinv + segment starts ----------------
__device__ inline void node_prep_dev(const int* deg, float* dinv, const int* batch,
                                     int* start, int i, int n, int G) {
  dinv[i] = rsqrtf((float)(deg[i] + 1));
  int b = batch[i];
  if (i == 0) { for (int g = 0; g <= b; ++g) start[g] = 0; }
  else { int pb = batch[i - 1]; for (int g = pb + 1; g <= b; ++g) start[g] = i; }
  if (i == n - 1) { for (int g = b + 1; g <= G; ++g) start[g] = n; }
}

__global__ void node_prep_kernel(const int* __restrict__ degP, float* __restrict__ dinvP,
                                 const int* __restrict__ batchP, int* __restrict__ startP, int nP,
                                 const int* __restrict__ degL, float* __restrict__ dinvL,
                                 const int* __restrict__ batchL, int* __restrict__ startL, int nL,
                                 int G) {
  int i = blockIdx.x * blockDim.x + threadIdx.x;
  if (i < nP) node_prep_dev(degP, dinvP, batchP, startP, i, nP, G);
  int j = i - nP;
  if (j >= 0 && j < nL) node_prep_dev(degL, dinvL, batchL, startL, j, nL, G);
}

// ---------------- W2 -> W2^T bf16 prep ----------------
__global__ void wprep_kernel(const float* __restrict__ Wp2, ushort_t* __restrict__ WtP,
                             const float* __restrict__ Wl2, ushort_t* __restrict__ WtL) {
  int i = blockIdx.x * blockDim.x + threadIdx.x;
  if (i < 16384) {
    int f = i >> 7, k = i & 127;
    WtP[i] = f2bf(Wp2[k * 128 + f]);
  } else if (i < 32768) {
    int j = i - 16384;
    int f = j >> 7, k = j & 127;
    WtL[j] = f2bf(Wl2[k * 128 + f]);
  }
}

// ---------------- hierarchical scan ----------------
__device__ inline void blocksum_dev(const int* cnt, int* bsum, int n, int b) {
  int t = threadIdx.x;
  int base = b * SCAN_CHUNK;
  int s = 0;
  for (int i = t; i < SCAN_CHUNK; i += 256) {
    int idx = base + i;
    if (idx < n) s += cnt[idx];
  }
  #pragma unroll
  for (int d = 32; d; d >>= 1) s += __shfl_down(s, d, 64);
  __shared__ int wt[4];
  int lane = t & 63, wid = t >> 6;
  if (lane == 0) wt[wid] = s;
  __syncthreads();
  if (t == 0) bsum[b] = wt[0] + wt[1] + wt[2] + wt[3];
}

__global__ __launch_bounds__(256) void blocksum2_kernel(
    const int* __restrict__ cntP, int nP, int nbP, int* __restrict__ bsumP,
    const int* __restrict__ cntL, int nL, int* __restrict__ bsumL) {
  int b = blockIdx.x;
  if (b < nbP) blocksum_dev(cntP, bsumP, nP, b);
  else blocksum_dev(cntL, bsumL, nL, b - nbP);
}

__device__ inline void exscan_small_dev(const int* bsum, int* boffs, int nb) {
  int t = threadIdx.x;
  int v = (t < nb) ? bsum[t] : 0;
  int lane = t & 63, wid = t >> 6;
  int inc = v;
  #pragma unroll
  for (int d = 1; d < 64; d <<= 1) {
    int u = __shfl_up(inc, d, 64);
    if (lane >= d) inc += u;
  }
  __shared__ int wt[16];
  if (lane == 63) wt[wid] = inc;
  __syncthreads();
  if (t < 16) {
    int w = wt[t];
    #pragma unroll
    for (int d = 1; d < 16; d <<= 1) {
      int u = __shfl_up(w, d, 64);
      if (t >= d) w += u;
    }
    wt[t] = w;
  }
  __syncthreads();
  int excl = (wid ? wt[wid - 1] : 0) + inc - v;
  if (t < nb) boffs[t] = excl;
  if (t == 0) boffs[nb] = wt[15];
}

__global__ __launch_bounds__(1024) void exscan2_kernel(const int* __restrict__ bsumP,
                                                       int* __restrict__ boffsP, int nbP,
                                                       const int* __restrict__ bsumL,
                                                       int* __restrict__ boffsL, int nbL) {
  if (blockIdx.x == 0) exscan_small_dev(bsumP, boffsP, nbP);
  else exscan_small_dev(bsumL, boffsL, nbL);
}

__device__ inline void scan_apply_dev(const int* cnt, const int* boffs, int* offs,
                                      int n, int nb, int b) {
  int t = threadIdx.x;
  int base = b * SCAN_CHUNK + t * 8;
  int v[8];
  int s = 0;
  #pragma unroll
  for (int j = 0; j < 8; ++j) {
    int idx = base + j;
    v[j] = (idx < n) ? cnt[idx] : 0;
    s += v[j];
  }
  int lane = t & 63, wid = t >> 6;
  int inc = s;
  #pragma unroll
  for (int d = 1; d < 64; d <<= 1) {
    int u = __shfl_up(inc, d, 64);
    if (lane >= d) inc += u;
  }
  __shared__ int wt[4];
  if (lane == 63) wt[wid] = inc;
  __syncthreads();
  int wadd = 0;
  for (int w = 0; w < wid; ++w) wadd += wt[w];
  int excl = boffs[b] + wadd + inc - s;
  #pragma unroll
  for (int j = 0; j < 8; ++j) {
    int idx = base + j;
    if (idx < n) offs[idx] = excl;
    excl += v[j];
  }
  if (b == 0 && t == 0) offs[n] = boffs[nb];
}

__global__ __launch_bounds__(256) void scan_apply2_kernel(
    const int* __restrict__ cntP, const int* __restrict__ boffsP, int* __restrict__ offsP,
    int nP, int nbP,
    const int* __restrict__ cntL, const int* __restrict__ boffsL, int* __restrict__ offsL,
    int nL, int nbL) {
  int b = blockIdx.x;
  if (b < nbP) scan_apply_dev(cntP, boffsP, offsP, nP, nbP, b);
  else scan_apply_dev(cntL, boffsL, offsL, nL, nbL, b - nbP);
}

// ---------------- scatter pass 1: bin (src,dst) pairs by dst bucket ----------
// Bucket b's region in the pair buffer == final CSR region [offs[b<<8], ...):
// sizes match exactly, so no extra counting pass is needed.
__global__ void bucket_pass1_kernel(
    const int* __restrict__ srcP, const int* __restrict__ dstP,
    const int* __restrict__ offsP, int* __restrict__ bcurP, int2* __restrict__ pairP, int Ep,
    const int* __restrict__ srcL, const int* __restrict__ dstL,
    const int* __restrict__ offsL, int* __restrict__ bcurL, int2* __restrict__ pairL, int El) {
  int e = blockIdx.x * blockDim.x + threadIdx.x;
  if (e < Ep) {
    int s = srcP[e], d = dstP[e];
    int b = d >> BSHIFT;
    int pos = offsP[b << BSHIFT] + atomicAdd(&bcurP[b], 1);
    pairP[pos] = make_int2(s, d);
  } else if (e < Ep + El) {
    int e2 = e - Ep;
    int s = srcL[e2], d = dstL[e2];
    int b = d >> BSHIFT;
    int pos = offsL[b << BSHIFT] + atomicAdd(&bcurL[b], 1);
    pairL[pos] = make_int2(s, d);
  }
}

// ---------------- scatter pass 2: one block per bucket, L2-local scatter -----
__global__ __launch_bounds__(256) void bucket_pass2_kernel(
    const int2* __restrict__ pairP, const int* __restrict__ offsP, int* __restrict__ curP,
    int* __restrict__ ssrcP, int nP, int nbkP,
    const int2* __restrict__ pairL, const int* __restrict__ offsL, int* __restrict__ curL,
    int* __restrict__ ssrcL, int nL) {
  int b = blockIdx.x;
  const int2* pair; const int* offs; int* cur; int* ssrc; int n;
  if (b < nbkP) { pair = pairP; offs = offsP; cur = curP; ssrc = ssrcP; n = nP; }
  else { b -= nbkP; pair = pairL; offs = offsL; cur = curL; ssrc = ssrcL; n = nL; }
  int lo = b << BSHIFT;
  int hi = lo + (1 << BSHIFT); if (hi > n) hi = n;
  int ebeg = offs[lo], eend = offs[hi];
  for (int i = ebeg + threadIdx.x; i < eend; i += 256) {
    int2 p = pair[i];
    int pos = offs[p.y] + atomicAdd(&cur[p.y], 1);
    ssrc[pos] = p.x;
  }
}

// ---------------- layer-1 aggregation: lane-grouped (LPG lanes per edge) ----
template<int F, int LPG>
__device__ inline void agg_small_dev(const float* __restrict__ x, const int* __restrict__ ssrc,
                                     const int* __restrict__ offs, const float* __restrict__ dinv,
                                     float* __restrict__ out, int node, int n) {
  if (node >= n) return;
  constexpr int G = 64 / LPG;  // edges in flight per wave
  int lane = threadIdx.x & 63;
  int grp = lane / LPG, l = lane % LPG;
  int beg = offs[node], end = offs[node + 1];
  float acc = 0.f;
  for (int b0 = beg; b0 < end; b0 += 64) {
    int m = end - b0; if (m > 64) m = 64;
    int sl = 0; float wl = 0.f;
    if (lane < m) { sl = ssrc[b0 + lane]; wl = dinv[sl]; }
    for (int k = 0; k < m; k += G) {
      int idx = k + grp;
      int s = __shfl(sl, idx, 64);
      float w = __shfl(wl, idx, 64);
      if (l < F) acc += x[(size_t)s * F + l] * w;
    }
  }
  #pragma unroll
  for (int d = LPG; d < 64; d <<= 1) acc += __shfl_xor(acc, d, 64);
  if (grp == 0 && l < F) {
    float di = dinv[node];
    acc = (acc + x[(size_t)node * F + l] * di) * di;
    out[(size_t)node * F + l] = acc;
  }
}

__global__ void agg1_both_kernel(const float* __restrict__ xP, const int* __restrict__ ssrcP,
                                 const int* __restrict__ offsP, const float* __restrict__ dinvP,
                                 float* __restrict__ outP, int nP, int nblkP,
                                 const float* __restrict__ xL, const int* __restrict__ ssrcL,
                                 const int* __restrict__ offsL, const float* __restrict__ dinvL,
                                 float* __restrict__ outL, int nL) {
  int wave_in_blk = threadIdx.x >> 6;
  if ((int)blockIdx.x < nblkP) {
    int node = blockIdx.x * 4 + wave_in_blk;
    agg_small_dev<23, 32>(xP, ssrcP, offsP, dinvP, outP, node, nP);
  } else {
    int node = (blockIdx.x - nblkP) * 4 + wave_in_blk;
    agg_small_dev<4, 4>(xL, ssrcL, offsL, dinvL, outL, node, nL);
  }
}

// ---------------- layer-2 aggregation: 4 edges/wave, 16B/lane uint4 ---------
// Table x holds h1' = h1 * dinv[src] (dinv folded at transform-1 epilogue),
// so aggregation is a pure sum: out = dinv[i]*(sum_{s} h1'[s] + h1'[i]).
__device__ inline void agg128v_dev(const ushort_t* __restrict__ x, const int* __restrict__ ssrc,
                                   const int* __restrict__ offs, const float* __restrict__ dinv,
                                   ushort_t* __restrict__ out, int node, int n) {
  if (node >= n) return;
  int lane = threadIdx.x & 63;
  int g = lane >> 4, l = lane & 15;
  int beg = offs[node], end = offs[node + 1];
  float acc[8];
  #pragma unroll
  for (int j = 0; j < 8; ++j) acc[j] = 0.f;
  const uint4* x4 = (const uint4*)x;  // 16B units; row = 16 units (128 bf16)
  for (int b0 = beg; b0 < end; b0 += 64) {
    int m = end - b0; if (m > 64) m = 64;
    int sl = 0;
    if (lane < m) sl = ssrc[b0 + lane];
    for (int k = 0; k < m; k += 4) {
      int s = __shfl(sl, k + g, 64);
      if (k + g < m) {
        uint4 v = x4[(size_t)s * 16 + l];
        acc[0] += bf2f((ushort_t)(v.x & 0xffff)); acc[1] += bf2f((ushort_t)(v.x >> 16));
        acc[2] += bf2f((ushort_t)(v.y & 0xffff)); acc[3] += bf2f((ushort_t)(v.y >> 16));
        acc[4] += bf2f((ushort_t)(v.z & 0xffff)); acc[5] += bf2f((ushort_t)(v.z >> 16));
        acc[6] += bf2f((ushort_t)(v.w & 0xffff)); acc[7] += bf2f((ushort_t)(v.w >> 16));
      }
    }
  }
  #pragma unroll
  for (int j = 0; j < 8; ++j) {
    acc[j] += __shfl_xor(acc[j], 16, 64);
    acc[j] += __shfl_xor(acc[j], 32, 64);
  }
  if (g == 0) {
    uint4 v = x4[(size_t)node * 16 + l];
    float di = dinv[node];
    float r0 = (acc[0] + bf2f((ushort_t)(v.x & 0xffff))) * di;
    float r1 = (acc[1] + bf2f((ushort_t)(v.x >> 16)))   * di;
    float r2 = (acc[2] + bf2f((ushort_t)(v.y & 0xffff))) * di;
    float r3 = (acc[3] + bf2f((ushort_t)(v.y >> 16)))   * di;
    float r4 = (acc[4] + bf2f((ushort_t)(v.z & 0xffff))) * di;
    float r5 = (acc[5] + bf2f((ushort_t)(v.z >> 16)))   * di;
    float r6 = (acc[6] + bf2f((ushort_t)(v.w & 0xffff))) * di;
    float r7 = (acc[7] + bf2f((ushort_t)(v.w >> 16)))   * di;
    uint4 o;
    o.x = pack2bf(r0, r1); o.y = pack2bf(r2, r3);
    o.z = pack2bf(r4, r5); o.w = pack2bf(r6, r7);
    ((uint4*)out)[(size_t)node * 16 + l] = o;
  }
}

__global__ void agg2_both_kernel(const ushort_t* __restrict__ xP, const int* __restrict__ ssrcP,
                                 const int* __restrict__ offsP, const float* __restrict__ dinvP,
                                 ushort_t* __restrict__ outP, int nP, int nblkP,
                                 const ushort_t* __restrict__ xL, const int* __restrict__ ssrcL,
                                 const int* __restrict__ offsL, const float* __restrict__ dinvL,
                                 ushort_t* __restrict__ outL, int nL) {
  int wv = threadIdx.x >> 6;
  if ((int)blockIdx.x < nblkP)
    agg128v_dev(xP, ssrcP, offsP, dinvP, outP, blockIdx.x * 4 + wv, nP);
  else
    agg128v_dev(xL, ssrcL, offsL, dinvL, outL, (blockIdx.x - nblkP) * 4 + wv, nL);
}

// ---------------- layer-1 transform (f32 VALU; K=23/4 not MFMA-shaped) -------
// Epilogue folds scale[node] (= dinv) so the table holds h1' = relu(...)*dinv.
template<int KIN, int NPB>
__device__ inline void transform_dev(float* smem, const float* __restrict__ in,
                                     const float* __restrict__ W, const float* __restrict__ bias,
                                     const float* __restrict__ scale,
                                     ushort_t* __restrict__ out, int n, int blk) {
  constexpr int KT = (KIN > 64) ? 64 : KIN;
  float* Ws = smem;                 // KT*128
  float* rowsT = smem + KT * 128;   // KIN*NPB, [k][j]
  const int f = threadIdx.x;
  const int base = blk * NPB;

  for (int i = f; i < NPB * KIN; i += 128) {
    int j = i / KIN, k = i - j * KIN;
    int node = base + j;
    rowsT[k * NPB + j] = (node < n) ? in[(size_t)node * KIN + k] : 0.f;
  }

  float acc[NPB];
  #pragma unroll
  for (int j = 0; j < NPB; ++j) acc[j] = 0.f;

  for (int k0 = 0; k0 < KIN; k0 += KT) {
    __syncthreads();
    int kt = KIN - k0; if (kt > KT) kt = KT;
    for (int i = f; i < kt * 128; i += 128) Ws[i] = W[(size_t)k0 * 128 + i];
    __syncthreads();
    for (int k = 0; k < kt; ++k) {
      float w = Ws[k * 128 + f];
      const float4* rt = (const float4*)&rowsT[(k0 + k) * NPB];
      #pragma unroll
      for (int j4 = 0; j4 < NPB / 4; ++j4) {
        float4 r = rt[j4];
        acc[j4 * 4 + 0] += r.x * w;
        acc[j4 * 4 + 1] += r.y * w;
        acc[j4 * 4 + 2] += r.z * w;
        acc[j4 * 4 + 3] += r.w * w;
      }
    }
  }
  float bv = bias[f];
  #pragma unroll
  for (int j = 0; j < NPB; ++j) {
    int node = base + j;
    if (node < n) {
      float v = fmaxf(acc[j] + bv, 0.f) * scale[node];
      out[(size_t)node * 128 + f] = f2bf(v);
    }
  }
}

__global__ __launch_bounds__(128) void transform1_both_kernel(
    const float* __restrict__ inP, const float* __restrict__ WP, const float* __restrict__ bP,
    const float* __restrict__ dinvP, ushort_t* __restrict__ outP, int nP, int nblkP,
    const float* __restrict__ inL, const float* __restrict__ WL, const float* __restrict__ bL,
    const float* __restrict__ dinvL, ushort_t* __restrict__ outL, int nL) {
  __shared__ float smem[23 * 128 + 23 * 16];
  if ((int)blockIdx.x < nblkP)
    transform_dev<23, 16>(smem, inP, WP, bP, dinvP, outP, nP, blockIdx.x);
  else
    transform_dev<4, 16>(smem, inL, WL, bL, dinvL, outL, nL, blockIdx.x - nblkP);
}

// ---------------- layer-2 transform via MFMA bf16 ----------------
__global__ __launch_bounds__(512) void t2_mfma_kernel(
    const ushort_t* __restrict__ aggP, const ushort_t* __restrict__ WtP,
    const float* __restrict__ bP, float* __restrict__ h2P, int nP, int nblkP,
    const ushort_t* __restrict__ aggL, const ushort_t* __restrict__ WtL,
    const float* __restrict__ bL, float* __restrict__ h2L, int nL) {
  const ushort_t* agg; const ushort_t* Wt; const float* bias; float* out; int n, n0;
  if ((int)blockIdx.x < nblkP) {
    agg = aggP; Wt = WtP; bias = bP; out = h2P; n = nP; n0 = blockIdx.x * 128;
  } else {
    agg = aggL; Wt = WtL; bias = bL; out = h2L; n = nL;
    n0 = (blockIdx.x - nblkP) * 128;
  }
  __shared__ __align__(16) short sB[16384];  // 32KB: 128 nodes x 128 k bf16
  const int t = threadIdx.x;
  const int lane = t & 63;
  const int ws = t >> 6;

  #pragma unroll
  for (int c4 = 0; c4 < 4; ++c4) {
    int cidx = t + c4 * 512;
    int node = cidx >> 4, c = cidx & 15;
    uint4 v = make_uint4(0u, 0u, 0u, 0u);
    if (n0 + node < n) v = *(const uint4*)&agg[(size_t)(n0 + node) * 128 + c * 8];
    int off16 = (((node >> 4) * 4 + (c >> 2)) * 64) + (c & 3) * 16 + (node & 15);
    *(uint4*)&sB[off16 * 8] = v;
  }

  const int fs = ws * 16;
  bf16x8 a[4];
  #pragma unroll
  for (int kc = 0; kc < 4; ++kc)
    a[kc] = *(const bf16x8*)&Wt[(size_t)(fs + (lane & 15)) * 128 + kc * 32 + (lane >> 4) * 8];

  __syncthreads();

  f32x4 acc[8];
  #pragma unroll
  for (int g = 0; g < 8; ++g) acc[g] = (f32x4){0.f, 0.f, 0.f, 0.f};

  #pragma unroll
  for (int g = 0; g < 8; ++g) {
    #pragma unroll
    for (int kc = 0; kc < 4; ++kc) {
      bf16x8 b = *(const bf16x8*)&sB[(((g * 4 + kc) * 64) + lane) * 8];
      acc[g] = __builtin_amdgcn_mfma_f32_16x16x32_bf16(a[kc], b, acc[g], 0, 0, 0);
    }
  }

  const int f0 = fs + ((lane >> 4) << 2);
  float4 bv = *(const float4*)&bias[f0];
  #pragma unroll
  for (int g = 0; g < 8; ++g) {
    int node = n0 + g * 16 + (lane & 15);
    if (node < n) {
      float4 o;
      o.x = fmaxf(acc[g][0] + bv.x, 0.f);
      o.y = fmaxf(acc[g][1] + bv.y, 0.f);
      o.z = fmaxf(acc[g][2] + bv.z, 0.f);
      o.w = fmaxf(acc[g][3] + bv.w, 0.f);
      *(float4*)&out[(size_t)node * 128 + f0] = o;
    }
  }
}

// ---------------- segmented mean-pool (both graphs) ----------------
__device__ inline void pool_dev(const float* __restrict__ h, const int* __restrict__ start,
                                float* __restrict__ mean, int g) {
  int t = threadIdx.x;
  int f = t & 127, r = t >> 7;
  int beg = start[g], end = start[g + 1];
  float acc = 0.f;
  for (int i = beg + r; i < end; i += 4)
    acc += h[(size_t)i * 128 + f];
  __shared__ float red[4][128];
  red[r][f] = acc;
  __syncthreads();
  if (r == 0) {
    float s = red[0][f] + red[1][f] + red[2][f] + red[3][f];
    float c = (float)(end - beg);
    mean[(size_t)g * 128 + f] = s / fmaxf(c, 1.f);
  }
}

__global__ __launch_bounds__(512) void pool_both_kernel(
    const float* __restrict__ hP, const int* __restrict__ startP, float* __restrict__ meanP,
    const float* __restrict__ hL, const int* __restrict__ startL, float* __restrict__ meanL,
    int G) {
  int g = blockIdx.x;
  if (g < G) pool_dev(hP, startP, meanP, g);
  else pool_dev(hL, startL, meanL, g - G);
}

// ---------------- final FC + 3 heads ----------------
__global__ __launch_bounds__(128) void fc_heads_kernel(
    const float* __restrict__ pe, const float* __restrict__ le,
    const float* __restrict__ Wfc, const float* __restrict__ bfc,
    const float* __restrict__ Wpkd, const float* __restrict__ bpkd,
    const float* __restrict__ Wpki, const float* __restrict__ bpki,
    const float* __restrict__ Wba, const float* __restrict__ bba,
    float* __restrict__ out, int G) {
  int g = blockIdx.x, f = threadIdx.x;
  __shared__ float comb[256];
  __shared__ float cbuf[128];
  comb[f]       = pe[(size_t)g * 128 + f];
  comb[128 + f] = le[(size_t)g * 128 + f];
  __syncthreads();
  float acc = bfc[f];
  for (int k = 0; k < 256; ++k) acc += comb[k] * Wfc[(size_t)k * 128 + f];
  cbuf[f] = fmaxf(acc, 0.f);
  __syncthreads();
  if (f < 64) {
    const float* Wh[3] = {Wpkd, Wpki, Wba};
    const float* bh[3] = {bpkd, bpki, bba};
    #pragma unroll
    for (int hd = 0; hd < 3; ++hd) {
      float v = cbuf[f] * Wh[hd][f] + cbuf[f + 64] * Wh[hd][f + 64];
      #pragma unroll
      for (int d = 32; d; d >>= 1) v += __shfl_xor(v, d, 64);
      if (f == 0) out[(size_t)hd * G + g] = v + bh[hd][0];
    }
  }
}

// ============================================================================
static inline size_t alignUp(size_t x, size_t a) { return (x + a - 1) / a * a; }

extern "C" void kernel_launch(void* const* d_in, const int* in_sizes, int n_in,
                              void* d_out, int out_size, void* d_ws, size_t ws_size,
                              hipStream_t stream) {
  const float* px     = (const float*)d_in[0];
  const int*   pei    = (const int*)d_in[1];
  const int*   pbatch = (const int*)d_in[2];
  const float* lx     = (const float*)d_in[3];
  const int*   lei    = (const int*)d_in[4];
  const int*   lbatch = (const int*)d_in[5];
  const float* Wp1 = (const float*)d_in[7],  *bp1 = (const float*)d_in[8];
  const float* Wp2 = (const float*)d_in[9],  *bp2 = (const float*)d_in[10];
  const float* Wl1 = (const float*)d_in[11], *bl1 = (const float*)d_in[12];
  const float* Wl2 = (const float*)d_in[13], *bl2 = (const float*)d_in[14];
  const float* Wfc = (const float*)d_in[15], *bfc = (const float*)d_in[16];
  const float* Wpkd = (const float*)d_in[17], *bpkd = (const float*)d_in[18];
  const float* Wpki = (const float*)d_in[19], *bpki = (const float*)d_in[20];
  const float* Wba  = (const float*)d_in[21], *bba  = (const float*)d_in[22];
  float* out = (float*)d_out;

  const int Np = in_sizes[0] / 23, Ep = in_sizes[1] / 2;
  const int Nl = in_sizes[3] / 4,  El = in_sizes[4] / 2;
  const int G  = out_size / 3;
  const int nb_p = (Np + SCAN_CHUNK - 1) / SCAN_CHUNK;
  const int nb_l = (Nl + SCAN_CHUNK - 1) / SCAN_CHUNK;
  const int nbk_p = (Np + (1 << BSHIFT) - 1) >> BSHIFT;   // scatter buckets
  const int nbk_l = (Nl + (1 << BSHIFT) - 1) >> BSHIFT;

  // ---- workspace layout ----
  char* base = (char*)d_ws;
  size_t off = 0;
  auto alloc = [&](size_t bytes) -> void* {
    void* p = base + off;
    off = alignUp(off + bytes, 256);
    return p;
  };
  size_t zero_beg = off;
  int*   degcnt_p = (int*)alloc((size_t)Np * 4);
  int*   cursor_p = (int*)alloc((size_t)Np * 4);
  int*   degcnt_l = (int*)alloc((size_t)Nl * 4);
  int*   cursor_l = (int*)alloc((size_t)Nl * 4);
  int*   bcur_p   = (int*)alloc((size_t)nbk_p * 4);
  int*   bcur_l   = (int*)alloc((size_t)nbk_l * 4);
  size_t zero_end = off;
  int*   offs_p  = (int*)alloc((size_t)(Np + 1) * 4);
  int*   offs_l  = (int*)alloc((size_t)(Nl + 1) * 4);
  int*   bsum_p  = (int*)alloc((size_t)nb_p * 4);
  int*   boffs_p = (int*)alloc((size_t)(nb_p + 1) * 4);
  int*   bsum_l  = (int*)alloc((size_t)nb_l * 4);
  int*   boffs_l = (int*)alloc((size_t)(nb_l + 1) * 4);
  int*   start_p = (int*)alloc((size_t)(G + 1) * 4);
  int*   start_l = (int*)alloc((size_t)(G + 1) * 4);
  float* dinv_p  = (float*)alloc((size_t)Np * 4);
  float* dinv_l  = (float*)alloc((size_t)Nl * 4);
  int*   ssrc_p  = (int*)alloc((size_t)Ep * 4);
  int*   ssrc_l  = (int*)alloc((size_t)El * 4);
  int2*  pair_p  = (int2*)alloc((size_t)Ep * 8);
  int2*  pair_l  = (int2*)alloc((size_t)El * 8);
  float* pe_mean = (float*)alloc((size_t)G * 128 * 4);
  float* le_mean = (float*)alloc((size_t)G * 128 * 4);
  ushort_t* wt2_p = (ushort_t*)alloc((size_t)16384 * 2);
  ushort_t* wt2_l = (ushort_t*)alloc((size_t)16384 * 2);
  float*    agg1_p = (float*)alloc((size_t)Np * 23 * 4);
  ushort_t* h1_p   = (ushort_t*)alloc((size_t)Np * 128 * 2);  // bf16 h1'=h1*dinv
  ushort_t* agg2_p = (ushort_t*)alloc((size_t)Np * 128 * 2);  // bf16
  float*    h2_p   = (float*)alloc((size_t)Np * 128 * 4);
  float*    agg1_l = (float*)alloc((size_t)Nl * 4 * 4);
  ushort_t* h1_l   = (ushort_t*)alloc((size_t)Nl * 128 * 2);  // bf16 h1'=h1*dinv
  ushort_t* agg2_l = (ushort_t*)alloc((size_t)Nl * 128 * 2);  // bf16
  float*    h2_l   = (float*)alloc((size_t)Nl * 128 * 4);
  if (off > ws_size) return;

  hipMemsetAsync(base + zero_beg, 0, zero_end - zero_beg, stream);

  const int* psrc = pei;
  const int* pdst = pei + Ep;
  const int* lsrc = lei;
  const int* ldst = lei + El;

  // ---- weight prep (independent) ----
  wprep_kernel<<<128, 256, 0, stream>>>(Wp2, wt2_p, Wl2, wt2_l);

  // ---- CSR build + per-node prep ----
  count_deg2_kernel<<<(Ep + El + 255) / 256, 256, 0, stream>>>(pdst, Ep, degcnt_p,
                                                               ldst, El, degcnt_l);
  node_prep_kernel<<<(Np + Nl + 255) / 256, 256, 0, stream>>>(
      degcnt_p, dinv_p, pbatch, start_p, Np,
      degcnt_l, dinv_l, lbatch, start_l, Nl, G);
  blocksum2_kernel<<<nb_p + nb_l, 256, 0, stream>>>(degcnt_p, Np, nb_p, bsum_p,
                                                    degcnt_l, Nl, bsum_l);
  exscan2_kernel<<<2, 1024, 0, stream>>>(bsum_p, boffs_p, nb_p, bsum_l, boffs_l, nb_l);
  scan_apply2_kernel<<<nb_p + nb_l, 256, 0, stream>>>(degcnt_p, boffs_p, offs_p, Np, nb_p,
                                                      degcnt_l, boffs_l, offs_l, Nl, nb_l);
  // 2-pass bucketed scatter (R5)
  bucket_pass1_kernel<<<(Ep + El + 255) / 256, 256, 0, stream>>>(
      psrc, pdst, offs_p, bcur_p, pair_p, Ep,
      lsrc, ldst, offs_l, bcur_l, pair_l, El);
  bucket_pass2_kernel<<<nbk_p + nbk_l, 256, 0, stream>>>(
      pair_p, offs_p, cursor_p, ssrc_p, Np, nbk_p,
      pair_l, offs_l, cursor_l, ssrc_l, Nl);

  // ---- GNN layer 1 (both graphs fused) ----
  const int ablkP = (Np + 3) / 4, ablkL = (Nl + 3) / 4;
  agg1_both_kernel<<<ablkP + ablkL, 256, 0, stream>>>(
      px, ssrc_p, offs_p, dinv_p, agg1_p, Np, ablkP,
      lx, ssrc_l, offs_l, dinv_l, agg1_l, Nl);
  const int tblkP = (Np + 15) / 16, tblkL = (Nl + 15) / 16;
  transform1_both_kernel<<<tblkP + tblkL, 128, 0, stream>>>(
      agg1_p, Wp1, bp1, dinv_p, h1_p, Np, tblkP,
      agg1_l, Wl1, bl1, dinv_l, h1_l, Nl);

  // ---- GNN layer 2 (both graphs fused) ----
  agg2_both_kernel<<<ablkP + ablkL, 256, 0, stream>>>(
      h1_p, ssrc_p, offs_p, dinv_p, agg2_p, Np, ablkP,
      h1_l, ssrc_l, offs_l, dinv_l, agg2_l, Nl);
  const int mblkP = (Np + 127) / 128, mblkL = (Nl + 127) / 128;
  t2_mfma_kernel<<<mblkP + mblkL, 512, 0, stream>>>(
      agg2_p, wt2_p, bp2, h2_p, Np, mblkP,
      agg2_l, wt2_l, bl2, h2_l, Nl);

  // ---- pool + FC/heads ----
  pool_both_kernel<<<2 * G, 512, 0, stream>>>(h2_p, start_p, pe_mean,
                                              h2_l, start_l, le_mean, G);
  fc_heads_kernel<<<G, 128, 0, stream>>>(pe_mean, le_mean, Wfc, bfc,
                                         Wpkd, bpkd, Wpki, bpki, Wba, bba, out, G);
}

// Round 7
// 416.946 us; speedup vs baseline: 2.3777x; 2.3777x over previous
//
#include <hip/hip_runtime.h>

// ============================================================================
// ProteinLigandGNN: 2x GCNConv (protein), 2x GCNConv (ligand), mean-pool,
// FC + 3 heads.
//
// GCNConv: out = D^-1/2 (A+I) D^-1/2 (X W) + b  ==  (D^-1/2 (A+I) D^-1/2 X) W + b
// Aggregate FIRST (narrow feature space when possible), then transform.
// R3: protein h1 bf16; fused P+L launches.
// R4: layer-2 transform via MFMA bf16; agg2/W2 bf16.
// R5: agg2 -> 4 edges/wave, 16B/lane uint4 gather; dinv folded into h1' table.
// R6: scatter binning redone as ZERO-global-atomic counting sort.
//     (R5's bucket_pass1 was 599us: 391 bucket counters x ~4100 atomics each
//      at ~146ns/same-address-atomic cross-XCD RMW. Lesson: contended global
//      atomics serialize at cross-XCD latency.)
//     bin_count: per-block LDS histogram -> cnt[block][bucket] (coalesced).
//     bin_scan:  per-bucket scan over blocks -> exact bases. No atomics.
//     bin_place: LDS cursors only -> (src,dst) pairs, bucket-contiguous.
//     bucket_pass2: per-bucket L2-local scatter into CSR (unchanged).
// ============================================================================

typedef unsigned short ushort_t;
typedef short bf16x8 __attribute__((ext_vector_type(8)));
typedef float f32x4 __attribute__((ext_vector_type(4)));

#define SCAN_CHUNK 2048
#define BSHIFT 8        // 256 dst nodes per scatter bucket
#define EPB 4096        // edges per binning block
#define MAXBK 1024      // max buckets (nodes <= 256k)

static __device__ inline ushort_t f2bf(float f) {  // RNE f32->bf16
  unsigned u = __float_as_uint(f);
  unsigned r = (u + 0x7FFFu + ((u >> 16) & 1u)) >> 16;
  return (ushort_t)r;
}
static __device__ inline float bf2f(ushort_t b) {
  return __uint_as_float((unsigned)b << 16);
}
static __device__ inline unsigned pack2bf(float lo, float hi) {
  return (unsigned)f2bf(lo) | ((unsigned)f2bf(hi) << 16);
}

// ---------------- fused degree count (both graphs) ----------------
__global__ void count_deg2_kernel(const int* __restrict__ dstP, int Ep, int* __restrict__ degP,
                                  const int* __restrict__ dstL, int El, int* __restrict__ degL) {
  int e = blockIdx.x * blockDim.x + threadIdx.x;
  if (e < Ep) atomicAdd(&degP[dstP[e]], 1);
  else if (e < Ep + El) atomicAdd(&degL[dstL[e - Ep]], 1);
}

// ---------------- fused per-node prep: dinv + segment starts ----------------
__device__ inline void node_prep_dev(const int* deg, float* dinv, const int* batch,
                                     int* start, int i, int n, int G) {
  dinv[i] = rsqrtf((float)(deg[i] + 1));
  int b = batch[i];
  if (i == 0) { for (int g = 0; g <= b; ++g) start[g] = 0; }
  else { int pb = batch[i - 1]; for (int g = pb + 1; g <= b; ++g) start[g] = i; }
  if (i == n - 1) { for (int g = b + 1; g <= G; ++g) start[g] = n; }
}

__global__ void node_prep_kernel(const int* __restrict__ degP, float* __restrict__ dinvP,
                                 const int* __restrict__ batchP, int* __restrict__ startP, int nP,
                                 const int* __restrict__ degL, float* __restrict__ dinvL,
                                 const int* __restrict__ batchL, int* __restrict__ startL, int nL,
                                 int G) {
  int i = blockIdx.x * blockDim.x + threadIdx.x;
  if (i < nP) node_prep_dev(degP, dinvP, batchP, startP, i, nP, G);
  int j = i - nP;
  if (j >= 0 && j < nL) node_prep_dev(degL, dinvL, batchL, startL, j, nL, G);
}

// ---------------- W2 -> W2^T bf16 prep ----------------
__global__ void wprep_kernel(const float* __restrict__ Wp2, ushort_t* __restrict__ WtP,
                             const float* __restrict__ Wl2, ushort_t* __restrict__ WtL) {
  int i = blockIdx.x * blockDim.x + threadIdx.x;
  if (i < 16384) {
    int f = i >> 7, k = i & 127;
    WtP[i] = f2bf(Wp2[k * 128 + f]);
  } else if (i < 32768) {
    int j = i - 16384;
    int f = j >> 7, k = j & 127;
    WtL[j] = f2bf(Wl2[k * 128 + f]);
  }
}

// ---------------- hierarchical scan (CSR offsets) ----------------
__device__ inline void blocksum_dev(const int* cnt, int* bsum, int n, int b) {
  int t = threadIdx.x;
  int base = b * SCAN_CHUNK;
  int s = 0;
  for (int i = t; i < SCAN_CHUNK; i += 256) {
    int idx = base + i;
    if (idx < n) s += cnt[idx];
  }
  #pragma unroll
  for (int d = 32; d; d >>= 1) s += __shfl_down(s, d, 64);
  __shared__ int wt[4];
  int lane = t & 63, wid = t >> 6;
  if (lane == 0) wt[wid] = s;
  __syncthreads();
  if (t == 0) bsum[b] = wt[0] + wt[1] + wt[2] + wt[3];
}

__global__ __launch_bounds__(256) void blocksum2_kernel(
    const int* __restrict__ cntP, int nP, int nbP, int* __restrict__ bsumP,
    const int* __restrict__ cntL, int nL, int* __restrict__ bsumL) {
  int b = blockIdx.x;
  if (b < nbP) blocksum_dev(cntP, bsumP, nP, b);
  else blocksum_dev(cntL, bsumL, nL, b - nbP);
}

__device__ inline void exscan_small_dev(const int* bsum, int* boffs, int nb) {
  int t = threadIdx.x;
  int v = (t < nb) ? bsum[t] : 0;
  int lane = t & 63, wid = t >> 6;
  int inc = v;
  #pragma unroll
  for (int d = 1; d < 64; d <<= 1) {
    int u = __shfl_up(inc, d, 64);
    if (lane >= d) inc += u;
  }
  __shared__ int wt[16];
  if (lane == 63) wt[wid] = inc;
  __syncthreads();
  if (t < 16) {
    int w = wt[t];
    #pragma unroll
    for (int d = 1; d < 16; d <<= 1) {
      int u = __shfl_up(w, d, 64);
      if (t >= d) w += u;
    }
    wt[t] = w;
  }
  __syncthreads();
  int excl = (wid ? wt[wid - 1] : 0) + inc - v;
  if (t < nb) boffs[t] = excl;
  if (t == 0) boffs[nb] = wt[15];
}

__global__ __launch_bounds__(1024) void exscan2_kernel(const int* __restrict__ bsumP,
                                                       int* __restrict__ boffsP, int nbP,
                                                       const int* __restrict__ bsumL,
                                                       int* __restrict__ boffsL, int nbL) {
  if (blockIdx.x == 0) exscan_small_dev(bsumP, boffsP, nbP);
  else exscan_small_dev(bsumL, boffsL, nbL);
}

__device__ inline void scan_apply_dev(const int* cnt, const int* boffs, int* offs,
                                      int n, int nb, int b) {
  int t = threadIdx.x;
  int base = b * SCAN_CHUNK + t * 8;
  int v[8];
  int s = 0;
  #pragma unroll
  for (int j = 0; j < 8; ++j) {
    int idx = base + j;
    v[j] = (idx < n) ? cnt[idx] : 0;
    s += v[j];
  }
  int lane = t & 63, wid = t >> 6;
  int inc = s;
  #pragma unroll
  for (int d = 1; d < 64; d <<= 1) {
    int u = __shfl_up(inc, d, 64);
    if (lane >= d) inc += u;
  }
  __shared__ int wt[4];
  if (lane == 63) wt[wid] = inc;
  __syncthreads();
  int wadd = 0;
  for (int w = 0; w < wid; ++w) wadd += wt[w];
  int excl = boffs[b] + wadd + inc - s;
  #pragma unroll
  for (int j = 0; j < 8; ++j) {
    int idx = base + j;
    if (idx < n) offs[idx] = excl;
    excl += v[j];
  }
  if (b == 0 && t == 0) offs[n] = boffs[nb];
}

__global__ __launch_bounds__(256) void scan_apply2_kernel(
    const int* __restrict__ cntP, const int* __restrict__ boffsP, int* __restrict__ offsP,
    int nP, int nbP,
    const int* __restrict__ cntL, const int* __restrict__ boffsL, int* __restrict__ offsL,
    int nL, int nbL) {
  int b = blockIdx.x;
  if (b < nbP) scan_apply_dev(cntP, boffsP, offsP, nP, nbP, b);
  else scan_apply_dev(cntL, boffsL, offsL, nL, nbL, b - nbP);
}

// ---------------- R6 binning: count (LDS histogram, no global atomics) ------
// cnt layout: cnt[(size_t)j * nbk + b]  (block-major: coalesced write here,
// coalesced read in bin_place; bin_scan takes the strided access).
__global__ __launch_bounds__(256) void bin_count_kernel(
    const int* __restrict__ dstP, int Ep, int nbkP, int nbeP, int* __restrict__ cntP,
    const int* __restrict__ dstL, int El, int nbkL, int* __restrict__ cntL) {
  __shared__ int hist[MAXBK];
  int j = blockIdx.x;
  const int* dst; int E, nbk; int* cnt;
  if (j < nbeP) { dst = dstP; E = Ep; nbk = nbkP; cnt = cntP; }
  else { j -= nbeP; dst = dstL; E = El; nbk = nbkL; cnt = cntL; }
  for (int i = threadIdx.x; i < nbk; i += 256) hist[i] = 0;
  __syncthreads();
  int e0 = j * EPB;
  for (int i = threadIdx.x; i < EPB; i += 256) {
    int e = e0 + i;
    if (e < E) atomicAdd(&hist[dst[e] >> BSHIFT], 1);
  }
  __syncthreads();
  for (int i = threadIdx.x; i < nbk; i += 256) cnt[(size_t)j * nbk + i] = hist[i];
}

// ---------------- R6 binning: per-bucket scan over blocks -> bases ----------
// In-place: m[j][b] becomes base of block j's run within bucket b's region.
__global__ __launch_bounds__(256) void bin_scan_kernel(
    const int* __restrict__ offsP, int nbkP, int nbeP, int* __restrict__ mP,
    const int* __restrict__ offsL, int nbkL, int nbeL, int* __restrict__ mL) {
  int b = blockIdx.x;
  const int* offs; int nbk, nbe; int* m;
  if (b < nbkP) { offs = offsP; nbk = nbkP; nbe = nbeP; m = mP; }
  else { b -= nbkP; offs = offsL; nbk = nbkL; nbe = nbeL; m = mL; }
  int t = threadIdx.x, lane = t & 63, wid = t >> 6;
  int j0 = 2 * t;
  int v0 = (j0     < nbe) ? m[(size_t)j0       * nbk + b] : 0;
  int v1 = (j0 + 1 < nbe) ? m[(size_t)(j0 + 1) * nbk + b] : 0;
  int s = v0 + v1;
  int inc = s;
  #pragma unroll
  for (int d = 1; d < 64; d <<= 1) {
    int u = __shfl_up(inc, d, 64);
    if (lane >= d) inc += u;
  }
  __shared__ int wt[4];
  if (lane == 63) wt[wid] = inc;
  __syncthreads();
  int wadd = 0;
  for (int w = 0; w < wid; ++w) wadd += wt[w];
  int excl = offs[b << BSHIFT] + wadd + inc - s;
  if (j0     < nbe) m[(size_t)j0       * nbk + b] = excl;
  if (j0 + 1 < nbe) m[(size_t)(j0 + 1) * nbk + b] = excl + v0;
}

// ---------------- R6 binning: place pairs (LDS cursors only) ----------------
__global__ __launch_bounds__(256) void bin_place_kernel(
    const int* __restrict__ srcP, const int* __restrict__ dstP, int Ep, int nbkP, int nbeP,
    const int* __restrict__ baseP, int2* __restrict__ pairP,
    const int* __restrict__ srcL, const int* __restrict__ dstL, int El, int nbkL,
    const int* __restrict__ baseL, int2* __restrict__ pairL) {
  __shared__ int lbase[MAXBK];
  int j = blockIdx.x;
  const int* src; const int* dst; int E, nbk; const int* base_m; int2* pair;
  if (j < nbeP) { src = srcP; dst = dstP; E = Ep; nbk = nbkP; base_m = baseP; pair = pairP; }
  else { j -= nbeP; src = srcL; dst = dstL; E = El; nbk = nbkL; base_m = baseL; pair = pairL; }
  for (int i = threadIdx.x; i < nbk; i += 256)
    lbase[i] = base_m[(size_t)j * nbk + i];
  __syncthreads();
  int e0 = j * EPB;
  for (int i = threadIdx.x; i < EPB; i += 256) {
    int e = e0 + i;
    if (e < E) {
      int s = src[e], d = dst[e];
      int pos = atomicAdd(&lbase[d >> BSHIFT], 1);
      pair[pos] = make_int2(s, d);
    }
  }
}

// ---------------- scatter pass 2: one block per bucket, L2-local scatter -----
__global__ __launch_bounds__(256) void bucket_pass2_kernel(
    const int2* __restrict__ pairP, const int* __restrict__ offsP, int* __restrict__ curP,
    int* __restrict__ ssrcP, int nP, int nbkP,
    const int2* __restrict__ pairL, const int* __restrict__ offsL, int* __restrict__ curL,
    int* __restrict__ ssrcL, int nL) {
  int b = blockIdx.x;
  const int2* pair; const int* offs; int* cur; int* ssrc; int n;
  if (b < nbkP) { pair = pairP; offs = offsP; cur = curP; ssrc = ssrcP; n = nP; }
  else { b -= nbkP; pair = pairL; offs = offsL; cur = curL; ssrc = ssrcL; n = nL; }
  int lo = b << BSHIFT;
  int hi = lo + (1 << BSHIFT); if (hi > n) hi = n;
  int ebeg = offs[lo], eend = offs[hi];
  for (int i = ebeg + threadIdx.x; i < eend; i += 256) {
    int2 p = pair[i];
    int pos = offs[p.y] + atomicAdd(&cur[p.y], 1);
    ssrc[pos] = p.x;
  }
}

// ---------------- layer-1 aggregation: lane-grouped (LPG lanes per edge) ----
template<int F, int LPG>
__device__ inline void agg_small_dev(const float* __restrict__ x, const int* __restrict__ ssrc,
                                     const int* __restrict__ offs, const float* __restrict__ dinv,
                                     float* __restrict__ out, int node, int n) {
  if (node >= n) return;
  constexpr int G = 64 / LPG;  // edges in flight per wave
  int lane = threadIdx.x & 63;
  int grp = lane / LPG, l = lane % LPG;
  int beg = offs[node], end = offs[node + 1];
  float acc = 0.f;
  for (int b0 = beg; b0 < end; b0 += 64) {
    int m = end - b0; if (m > 64) m = 64;
    int sl = 0; float wl = 0.f;
    if (lane < m) { sl = ssrc[b0 + lane]; wl = dinv[sl]; }
    for (int k = 0; k < m; k += G) {
      int idx = k + grp;
      int s = __shfl(sl, idx, 64);
      float w = __shfl(wl, idx, 64);
      if (l < F) acc += x[(size_t)s * F + l] * w;
    }
  }
  #pragma unroll
  for (int d = LPG; d < 64; d <<= 1) acc += __shfl_xor(acc, d, 64);
  if (grp == 0 && l < F) {
    float di = dinv[node];
    acc = (acc + x[(size_t)node * F + l] * di) * di;
    out[(size_t)node * F + l] = acc;
  }
}

__global__ void agg1_both_kernel(const float* __restrict__ xP, const int* __restrict__ ssrcP,
                                 const int* __restrict__ offsP, const float* __restrict__ dinvP,
                                 float* __restrict__ outP, int nP, int nblkP,
                                 const float* __restrict__ xL, const int* __restrict__ ssrcL,
                                 const int* __restrict__ offsL, const float* __restrict__ dinvL,
                                 float* __restrict__ outL, int nL) {
  int wave_in_blk = threadIdx.x >> 6;
  if ((int)blockIdx.x < nblkP) {
    int node = blockIdx.x * 4 + wave_in_blk;
    agg_small_dev<23, 32>(xP, ssrcP, offsP, dinvP, outP, node, nP);
  } else {
    int node = (blockIdx.x - nblkP) * 4 + wave_in_blk;
    agg_small_dev<4, 4>(xL, ssrcL, offsL, dinvL, outL, node, nL);
  }
}

// ---------------- layer-2 aggregation: 4 edges/wave, 16B/lane uint4 ---------
// Table x holds h1' = h1 * dinv[src] (folded at transform-1 epilogue).
__device__ inline void agg128v_dev(const ushort_t* __restrict__ x, const int* __restrict__ ssrc,
                                   const int* __restrict__ offs, const float* __restrict__ dinv,
                                   ushort_t* __restrict__ out, int node, int n) {
  if (node >= n) return;
  int lane = threadIdx.x & 63;
  int g = lane >> 4, l = lane & 15;
  int beg = offs[node], end = offs[node + 1];
  float acc[8];
  #pragma unroll
  for (int j = 0; j < 8; ++j) acc[j] = 0.f;
  const uint4* x4 = (const uint4*)x;  // 16B units; row = 16 units (128 bf16)
  for (int b0 = beg; b0 < end; b0 += 64) {
    int m = end - b0; if (m > 64) m = 64;
    int sl = 0;
    if (lane < m) sl = ssrc[b0 + lane];
    for (int k = 0; k < m; k += 4) {
      int s = __shfl(sl, k + g, 64);
      if (k + g < m) {
        uint4 v = x4[(size_t)s * 16 + l];
        acc[0] += bf2f((ushort_t)(v.x & 0xffff)); acc[1] += bf2f((ushort_t)(v.x >> 16));
        acc[2] += bf2f((ushort_t)(v.y & 0xffff)); acc[3] += bf2f((ushort_t)(v.y >> 16));
        acc[4] += bf2f((ushort_t)(v.z & 0xffff)); acc[5] += bf2f((ushort_t)(v.z >> 16));
        acc[6] += bf2f((ushort_t)(v.w & 0xffff)); acc[7] += bf2f((ushort_t)(v.w >> 16));
      }
    }
  }
  #pragma unroll
  for (int j = 0; j < 8; ++j) {
    acc[j] += __shfl_xor(acc[j], 16, 64);
    acc[j] += __shfl_xor(acc[j], 32, 64);
  }
  if (g == 0) {
    uint4 v = x4[(size_t)node * 16 + l];
    float di = dinv[node];
    float r0 = (acc[0] + bf2f((ushort_t)(v.x & 0xffff))) * di;
    float r1 = (acc[1] + bf2f((ushort_t)(v.x >> 16)))   * di;
    float r2 = (acc[2] + bf2f((ushort_t)(v.y & 0xffff))) * di;
    float r3 = (acc[3] + bf2f((ushort_t)(v.y >> 16)))   * di;
    float r4 = (acc[4] + bf2f((ushort_t)(v.z & 0xffff))) * di;
    float r5 = (acc[5] + bf2f((ushort_t)(v.z >> 16)))   * di;
    float r6 = (acc[6] + bf2f((ushort_t)(v.w & 0xffff))) * di;
    float r7 = (acc[7] + bf2f((ushort_t)(v.w >> 16)))   * di;
    uint4 o;
    o.x = pack2bf(r0, r1); o.y = pack2bf(r2, r3);
    o.z = pack2bf(r4, r5); o.w = pack2bf(r6, r7);
    ((uint4*)out)[(size_t)node * 16 + l] = o;
  }
}

__global__ void agg2_both_kernel(const ushort_t* __restrict__ xP, const int* __restrict__ ssrcP,
                                 const int* __restrict__ offsP, const float* __restrict__ dinvP,
                                 ushort_t* __restrict__ outP, int nP, int nblkP,
                                 const ushort_t* __restrict__ xL, const int* __restrict__ ssrcL,
                                 const int* __restrict__ offsL, const float* __restrict__ dinvL,
                                 ushort_t* __restrict__ outL, int nL) {
  int wv = threadIdx.x >> 6;
  if ((int)blockIdx.x < nblkP)
    agg128v_dev(xP, ssrcP, offsP, dinvP, outP, blockIdx.x * 4 + wv, nP);
  else
    agg128v_dev(xL, ssrcL, offsL, dinvL, outL, (blockIdx.x - nblkP) * 4 + wv, nL);
}

// ---------------- layer-1 transform (f32 VALU; K=23/4 not MFMA-shaped) -------
// Epilogue folds scale[node] (= dinv) so the table holds h1' = relu(...)*dinv.
template<int KIN, int NPB>
__device__ inline void transform_dev(float* smem, const float* __restrict__ in,
                                     const float* __restrict__ W, const float* __restrict__ bias,
                                     const float* __restrict__ scale,
                                     ushort_t* __restrict__ out, int n, int blk) {
  constexpr int KT = (KIN > 64) ? 64 : KIN;
  float* Ws = smem;                 // KT*128
  float* rowsT = smem + KT * 128;   // KIN*NPB, [k][j]
  const int f = threadIdx.x;
  const int base = blk * NPB;

  for (int i = f; i < NPB * KIN; i += 128) {
    int j = i / KIN, k = i - j * KIN;
    int node = base + j;
    rowsT[k * NPB + j] = (node < n) ? in[(size_t)node * KIN + k] : 0.f;
  }

  float acc[NPB];
  #pragma unroll
  for (int j = 0; j < NPB; ++j) acc[j] = 0.f;

  for (int k0 = 0; k0 < KIN; k0 += KT) {
    __syncthreads();
    int kt = KIN - k0; if (kt > KT) kt = KT;
    for (int i = f; i < kt * 128; i += 128) Ws[i] = W[(size_t)k0 * 128 + i];
    __syncthreads();
    for (int k = 0; k < kt; ++k) {
      float w = Ws[k * 128 + f];
      const float4* rt = (const float4*)&rowsT[(k0 + k) * NPB];
      #pragma unroll
      for (int j4 = 0; j4 < NPB / 4; ++j4) {
        float4 r = rt[j4];
        acc[j4 * 4 + 0] += r.x * w;
        acc[j4 * 4 + 1] += r.y * w;
        acc[j4 * 4 + 2] += r.z * w;
        acc[j4 * 4 + 3] += r.w * w;
      }
    }
  }
  float bv = bias[f];
  #pragma unroll
  for (int j = 0; j < NPB; ++j) {
    int node = base + j;
    if (node < n) {
      float v = fmaxf(acc[j] + bv, 0.f) * scale[node];
      out[(size_t)node * 128 + f] = f2bf(v);
    }
  }
}

__global__ __launch_bounds__(128) void transform1_both_kernel(
    const float* __restrict__ inP, const float* __restrict__ WP, const float* __restrict__ bP,
    const float* __restrict__ dinvP, ushort_t* __restrict__ outP, int nP, int nblkP,
    const float* __restrict__ inL, const float* __restrict__ WL, const float* __restrict__ bL,
    const float* __restrict__ dinvL, ushort_t* __restrict__ outL, int nL) {
  __shared__ float smem[23 * 128 + 23 * 16];
  if ((int)blockIdx.x < nblkP)
    transform_dev<23, 16>(smem, inP, WP, bP, dinvP, outP, nP, blockIdx.x);
  else
    transform_dev<4, 16>(smem, inL, WL, bL, dinvL, outL, nL, blockIdx.x - nblkP);
}

// ---------------- layer-2 transform via MFMA bf16 ----------------
__global__ __launch_bounds__(512) void t2_mfma_kernel(
    const ushort_t* __restrict__ aggP, const ushort_t* __restrict__ WtP,
    const float* __restrict__ bP, float* __restrict__ h2P, int nP, int nblkP,
    const ushort_t* __restrict__ aggL, const ushort_t* __restrict__ WtL,
    const float* __restrict__ bL, float* __restrict__ h2L, int nL) {
  const ushort_t* agg; const ushort_t* Wt; const float* bias; float* out; int n, n0;
  if ((int)blockIdx.x < nblkP) {
    agg = aggP; Wt = WtP; bias = bP; out = h2P; n = nP; n0 = blockIdx.x * 128;
  } else {
    agg = aggL; Wt = WtL; bias = bL; out = h2L; n = nL;
    n0 = (blockIdx.x - nblkP) * 128;
  }
  __shared__ __align__(16) short sB[16384];  // 32KB: 128 nodes x 128 k bf16
  const int t = threadIdx.x;
  const int lane = t & 63;
  const int ws = t >> 6;

  #pragma unroll
  for (int c4 = 0; c4 < 4; ++c4) {
    int cidx = t + c4 * 512;
    int node = cidx >> 4, c = cidx & 15;
    uint4 v = make_uint4(0u, 0u, 0u, 0u);
    if (n0 + node < n) v = *(const uint4*)&agg[(size_t)(n0 + node) * 128 + c * 8];
    int off16 = (((node >> 4) * 4 + (c >> 2)) * 64) + (c & 3) * 16 + (node & 15);
    *(uint4*)&sB[off16 * 8] = v;
  }

  const int fs = ws * 16;
  bf16x8 a[4];
  #pragma unroll
  for (int kc = 0; kc < 4; ++kc)
    a[kc] = *(const bf16x8*)&Wt[(size_t)(fs + (lane & 15)) * 128 + kc * 32 + (lane >> 4) * 8];

  __syncthreads();

  f32x4 acc[8];
  #pragma unroll
  for (int g = 0; g < 8; ++g) acc[g] = (f32x4){0.f, 0.f, 0.f, 0.f};

  #pragma unroll
  for (int g = 0; g < 8; ++g) {
    #pragma unroll
    for (int kc = 0; kc < 4; ++kc) {
      bf16x8 b = *(const bf16x8*)&sB[(((g * 4 + kc) * 64) + lane) * 8];
      acc[g] = __builtin_amdgcn_mfma_f32_16x16x32_bf16(a[kc], b, acc[g], 0, 0, 0);
    }
  }

  const int f0 = fs + ((lane >> 4) << 2);
  float4 bv = *(const float4*)&bias[f0];
  #pragma unroll
  for (int g = 0; g < 8; ++g) {
    int node = n0 + g * 16 + (lane & 15);
    if (node < n) {
      float4 o;
      o.x = fmaxf(acc[g][0] + bv.x, 0.f);
      o.y = fmaxf(acc[g][1] + bv.y, 0.f);
      o.z = fmaxf(acc[g][2] + bv.z, 0.f);
      o.w = fmaxf(acc[g][3] + bv.w, 0.f);
      *(float4*)&out[(size_t)node * 128 + f0] = o;
    }
  }
}

// ---------------- segmented mean-pool (both graphs) ----------------
__device__ inline void pool_dev(const float* __restrict__ h, const int* __restrict__ start,
                                float* __restrict__ mean, int g) {
  int t = threadIdx.x;
  int f = t & 127, r = t >> 7;
  int beg = start[g], end = start[g + 1];
  float acc = 0.f;
  for (int i = beg + r; i < end; i += 4)
    acc += h[(size_t)i * 128 + f];
  __shared__ float red[4][128];
  red[r][f] = acc;
  __syncthreads();
  if (r == 0) {
    float s = red[0][f] + red[1][f] + red[2][f] + red[3][f];
    float c = (float)(end - beg);
    mean[(size_t)g * 128 + f] = s / fmaxf(c, 1.f);
  }
}

__global__ __launch_bounds__(512) void pool_both_kernel(
    const float* __restrict__ hP, const int* __restrict__ startP, float* __restrict__ meanP,
    const float* __restrict__ hL, const int* __restrict__ startL, float* __restrict__ meanL,
    int G) {
  int g = blockIdx.x;
  if (g < G) pool_dev(hP, startP, meanP, g);
  else pool_dev(hL, startL, meanL, g - G);
}

// ---------------- final FC + 3 heads ----------------
__global__ __launch_bounds__(128) void fc_heads_kernel(
    const float* __restrict__ pe, const float* __restrict__ le,
    const float* __restrict__ Wfc, const float* __restrict__ bfc,
    const float* __restrict__ Wpkd, const float* __restrict__ bpkd,
    const float* __restrict__ Wpki, const float* __restrict__ bpki,
    const float* __restrict__ Wba, const float* __restrict__ bba,
    float* __restrict__ out, int G) {
  int g = blockIdx.x, f = threadIdx.x;
  __shared__ float comb[256];
  __shared__ float cbuf[128];
  comb[f]       = pe[(size_t)g * 128 + f];
  comb[128 + f] = le[(size_t)g * 128 + f];
  __syncthreads();
  float acc = bfc[f];
  for (int k = 0; k < 256; ++k) acc += comb[k] * Wfc[(size_t)k * 128 + f];
  cbuf[f] = fmaxf(acc, 0.f);
  __syncthreads();
  if (f < 64) {
    const float* Wh[3] = {Wpkd, Wpki, Wba};
    const float* bh[3] = {bpkd, bpki, bba};
    #pragma unroll
    for (int hd = 0; hd < 3; ++hd) {
      float v = cbuf[f] * Wh[hd][f] + cbuf[f + 64] * Wh[hd][f + 64];
      #pragma unroll
      for (int d = 32; d; d >>= 1) v += __shfl_xor(v, d, 64);
      if (f == 0) out[(size_t)hd * G + g] = v + bh[hd][0];
    }
  }
}

// ============================================================================
static inline size_t alignUp(size_t x, size_t a) { return (x + a - 1) / a * a; }

extern "C" void kernel_launch(void* const* d_in, const int* in_sizes, int n_in,
                              void* d_out, int out_size, void* d_ws, size_t ws_size,
                              hipStream_t stream) {
  const float* px     = (const float*)d_in[0];
  const int*   pei    = (const int*)d_in[1];
  const int*   pbatch = (const int*)d_in[2];
  const float* lx     = (const float*)d_in[3];
  const int*   lei    = (const int*)d_in[4];
  const int*   lbatch = (const int*)d_in[5];
  const float* Wp1 = (const float*)d_in[7],  *bp1 = (const float*)d_in[8];
  const float* Wp2 = (const float*)d_in[9],  *bp2 = (const float*)d_in[10];
  const float* Wl1 = (const float*)d_in[11], *bl1 = (const float*)d_in[12];
  const float* Wl2 = (const float*)d_in[13], *bl2 = (const float*)d_in[14];
  const float* Wfc = (const float*)d_in[15], *bfc = (const float*)d_in[16];
  const float* Wpkd = (const float*)d_in[17], *bpkd = (const float*)d_in[18];
  const float* Wpki = (const float*)d_in[19], *bpki = (const float*)d_in[20];
  const float* Wba  = (const float*)d_in[21], *bba  = (const float*)d_in[22];
  float* out = (float*)d_out;

  const int Np = in_sizes[0] / 23, Ep = in_sizes[1] / 2;
  const int Nl = in_sizes[3] / 4,  El = in_sizes[4] / 2;
  const int G  = out_size / 3;
  const int nb_p = (Np + SCAN_CHUNK - 1) / SCAN_CHUNK;
  const int nb_l = (Nl + SCAN_CHUNK - 1) / SCAN_CHUNK;
  const int nbk_p = (Np + (1 << BSHIFT) - 1) >> BSHIFT;   // scatter buckets
  const int nbk_l = (Nl + (1 << BSHIFT) - 1) >> BSHIFT;
  const int nbe_p = (Ep + EPB - 1) / EPB;                 // binning blocks
  const int nbe_l = (El + EPB - 1) / EPB;

  // ---- workspace layout ----
  char* base = (char*)d_ws;
  size_t off = 0;
  auto alloc = [&](size_t bytes) -> void* {
    void* p = base + off;
    off = alignUp(off + bytes, 256);
    return p;
  };
  size_t zero_beg = off;
  int*   degcnt_p = (int*)alloc((size_t)Np * 4);
  int*   cursor_p = (int*)alloc((size_t)Np * 4);
  int*   degcnt_l = (int*)alloc((size_t)Nl * 4);
  int*   cursor_l = (int*)alloc((size_t)Nl * 4);
  size_t zero_end = off;
  int*   offs_p  = (int*)alloc((size_t)(Np + 1) * 4);
  int*   offs_l  = (int*)alloc((size_t)(Nl + 1) * 4);
  int*   bsum_p  = (int*)alloc((size_t)nb_p * 4);
  int*   boffs_p = (int*)alloc((size_t)(nb_p + 1) * 4);
  int*   bsum_l  = (int*)alloc((size_t)nb_l * 4);
  int*   boffs_l = (int*)alloc((size_t)(nb_l + 1) * 4);
  int*   start_p = (int*)alloc((size_t)(G + 1) * 4);
  int*   start_l = (int*)alloc((size_t)(G + 1) * 4);
  float* dinv_p  = (float*)alloc((size_t)Np * 4);
  float* dinv_l  = (float*)alloc((size_t)Nl * 4);
  int*   ssrc_p  = (int*)alloc((size_t)Ep * 4);
  int*   ssrc_l  = (int*)alloc((size_t)El * 4);
  int2*  pair_p  = (int2*)alloc((size_t)Ep * 8);
  int2*  pair_l  = (int2*)alloc((size_t)El * 8);
  int*   cmat_p  = (int*)alloc((size_t)nbe_p * nbk_p * 4);  // [block][bucket]
  int*   cmat_l  = (int*)alloc((size_t)nbe_l * nbk_l * 4);
  float* pe_mean = (float*)alloc((size_t)G * 128 * 4);
  float* le_mean = (float*)alloc((size_t)G * 128 * 4);
  ushort_t* wt2_p = (ushort_t*)alloc((size_t)16384 * 2);
  ushort_t* wt2_l = (ushort_t*)alloc((size_t)16384 * 2);
  float*    agg1_p = (float*)alloc((size_t)Np * 23 * 4);
  ushort_t* h1_p   = (ushort_t*)alloc((size_t)Np * 128 * 2);  // bf16 h1'=h1*dinv
  ushort_t* agg2_p = (ushort_t*)alloc((size_t)Np * 128 * 2);  // bf16
  float*    h2_p   = (float*)alloc((size_t)Np * 128 * 4);
  float*    agg1_l = (float*)alloc((size_t)Nl * 4 * 4);
  ushort_t* h1_l   = (ushort_t*)alloc((size_t)Nl * 128 * 2);  // bf16 h1'=h1*dinv
  ushort_t* agg2_l = (ushort_t*)alloc((size_t)Nl * 128 * 2);  // bf16
  float*    h2_l   = (float*)alloc((size_t)Nl * 128 * 4);
  if (off > ws_size) return;

  hipMemsetAsync(base + zero_beg, 0, zero_end - zero_beg, stream);

  const int* psrc = pei;
  const int* pdst = pei + Ep;
  const int* lsrc = lei;
  const int* ldst = lei + El;

  // ---- weight prep (independent) ----
  wprep_kernel<<<128, 256, 0, stream>>>(Wp2, wt2_p, Wl2, wt2_l);

  // ---- CSR build + per-node prep ----
  count_deg2_kernel<<<(Ep + El + 255) / 256, 256, 0, stream>>>(pdst, Ep, degcnt_p,
                                                               ldst, El, degcnt_l);
  node_prep_kernel<<<(Np + Nl + 255) / 256, 256, 0, stream>>>(
      degcnt_p, dinv_p, pbatch, start_p, Np,
      degcnt_l, dinv_l, lbatch, start_l, Nl, G);
  blocksum2_kernel<<<nb_p + nb_l, 256, 0, stream>>>(degcnt_p, Np, nb_p, bsum_p,
                                                    degcnt_l, Nl, bsum_l);
  exscan2_kernel<<<2, 1024, 0, stream>>>(bsum_p, boffs_p, nb_p, bsum_l, boffs_l, nb_l);
  scan_apply2_kernel<<<nb_p + nb_l, 256, 0, stream>>>(degcnt_p, boffs_p, offs_p, Np, nb_p,
                                                      degcnt_l, boffs_l, offs_l, Nl, nb_l);

  // ---- R6 binning (zero global atomics) + bucket-local scatter ----
  bin_count_kernel<<<nbe_p + nbe_l, 256, 0, stream>>>(
      pdst, Ep, nbk_p, nbe_p, cmat_p,
      ldst, El, nbk_l, cmat_l);
  bin_scan_kernel<<<nbk_p + nbk_l, 256, 0, stream>>>(
      offs_p, nbk_p, nbe_p, cmat_p,
      offs_l, nbk_l, nbe_l, cmat_l);
  bin_place_kernel<<<nbe_p + nbe_l, 256, 0, stream>>>(
      psrc, pdst, Ep, nbk_p, nbe_p, cmat_p, pair_p,
      lsrc, ldst, El, nbk_l, cmat_l, pair_l);
  bucket_pass2_kernel<<<nbk_p + nbk_l, 256, 0, stream>>>(
      pair_p, offs_p, cursor_p, ssrc_p, Np, nbk_p,
      pair_l, offs_l, cursor_l, ssrc_l, Nl);

  // ---- GNN layer 1 (both graphs fused) ----
  const int ablkP = (Np + 3) / 4, ablkL = (Nl + 3) / 4;
  agg1_both_kernel<<<ablkP + ablkL, 256, 0, stream>>>(
      px, ssrc_p, offs_p, dinv_p, agg1_p, Np, ablkP,
      lx, ssrc_l, offs_l, dinv_l, agg1_l, Nl);
  const int tblkP = (Np + 15) / 16, tblkL = (Nl + 15) / 16;
  transform1_both_kernel<<<tblkP + tblkL, 128, 0, stream>>>(
      agg1_p, Wp1, bp1, dinv_p, h1_p, Np, tblkP,
      agg1_l, Wl1, bl1, dinv_l, h1_l, Nl);

  // ---- GNN layer 2 (both graphs fused) ----
  agg2_both_kernel<<<ablkP + ablkL, 256, 0, stream>>>(
      h1_p, ssrc_p, offs_p, dinv_p, agg2_p, Np, ablkP,
      h1_l, ssrc_l, offs_l, dinv_l, agg2_l, Nl);
  const int mblkP = (Np + 127) / 128, mblkL = (Nl + 127) / 128;
  t2_mfma_kernel<<<mblkP + mblkL, 512, 0, stream>>>(
      agg2_p, wt2_p, bp2, h2_p, Np, mblkP,
      agg2_l, wt2_l, bl2, h2_l, Nl);

  // ---- pool + FC/heads ----
  pool_both_kernel<<<2 * G, 512, 0, stream>>>(h2_p, start_p, pe_mean,
                                              h2_l, start_l, le_mean, G);
  fc_heads_kernel<<<G, 128, 0, stream>>>(pe_mean, le_mean, Wfc, bfc,
                                         Wpkd, bpkd, Wpki, bpki, Wba, bba, out, G);
}

// Round 8
// 364.040 us; speedup vs baseline: 2.7233x; 1.1453x over previous
//
#include <hip/hip_runtime.h>

// ============================================================================
// ProteinLigandGNN: 2x GCNConv (protein), 2x GCNConv (ligand), mean-pool,
// FC + 3 heads.
//
// GCNConv: out = D^-1/2 (A+I) D^-1/2 (X W) + b  ==  (D^-1/2 (A+I) D^-1/2 X) W + b
// Aggregate FIRST (narrow feature space when possible), then transform.
// R3: protein h1 bf16; fused P+L launches.
// R4: layer-2 transform via MFMA bf16; agg2/W2 bf16.
// R5: agg2 -> 4 edges/wave, 16B/lane uint4 gather; dinv folded into h1' table.
// R6: zero-global-atomic counting-sort binning (lesson: contended global
//     atomics serialize at ~146ns/op cross-XCD RMW).
// R7: transform1 FUSED into agg1 (was a standalone 80us kernel: VGPR=200 ->
//     10% occupancy, 726k LDS bank conflicts). The 23/4-dim aggregate is
//     already in wave registers; project to 128 features via F shfl
//     broadcasts + 2F FMA/lane with W1 staged as float2 pairs in LDS.
//     Removes the [n][KIN] f32 intermediate entirely.
// ============================================================================

typedef unsigned short ushort_t;
typedef short bf16x8 __attribute__((ext_vector_type(8)));
typedef float f32x4 __attribute__((ext_vector_type(4)));

#define SCAN_CHUNK 2048
#define BSHIFT 8        // 256 dst nodes per scatter bucket
#define EPB 4096        // edges per binning block
#define MAXBK 1024      // max buckets (nodes <= 256k)

static __device__ inline ushort_t f2bf(float f) {  // RNE f32->bf16
  unsigned u = __float_as_uint(f);
  unsigned r = (u + 0x7FFFu + ((u >> 16) & 1u)) >> 16;
  return (ushort_t)r;
}
static __device__ inline float bf2f(ushort_t b) {
  return __uint_as_float((unsigned)b << 16);
}
static __device__ inline unsigned pack2bf(float lo, float hi) {
  return (unsigned)f2bf(lo) | ((unsigned)f2bf(hi) << 16);
}

// ---------------- fused degree count (both graphs) ----------------
__global__ void count_deg2_kernel(const int* __restrict__ dstP, int Ep, int* __restrict__ degP,
                                  const int* __restrict__ dstL, int El, int* __restrict__ degL) {
  int e = blockIdx.x * blockDim.x + threadIdx.x;
  if (e < Ep) atomicAdd(&degP[dstP[e]], 1);
  else if (e < Ep + El) atomicAdd(&degL[dstL[e - Ep]], 1);
}

// ---------------- fused per-node prep: dinv + segment starts ----------------
__device__ inline void node_prep_dev(const int* deg, float* dinv, const int* batch,
                                     int* start, int i, int n, int G) {
  dinv[i] = rsqrtf((float)(deg[i] + 1));
  int b = batch[i];
  if (i == 0) { for (int g = 0; g <= b; ++g) start[g] = 0; }
  else { int pb = batch[i - 1]; for (int g = pb + 1; g <= b; ++g) start[g] = i; }
  if (i == n - 1) { for (int g = b + 1; g <= G; ++g) start[g] = n; }
}

__global__ void node_prep_kernel(const int* __restrict__ degP, float* __restrict__ dinvP,
                                 const int* __restrict__ batchP, int* __restrict__ startP, int nP,
                                 const int* __restrict__ degL, float* __restrict__ dinvL,
                                 const int* __restrict__ batchL, int* __restrict__ startL, int nL,
                                 int G) {
  int i = blockIdx.x * blockDim.x + threadIdx.x;
  if (i < nP) node_prep_dev(degP, dinvP, batchP, startP, i, nP, G);
  int j = i - nP;
  if (j >= 0 && j < nL) node_prep_dev(degL, dinvL, batchL, startL, j, nL, G);
}

// ---------------- W2 -> W2^T bf16 prep ----------------
__global__ void wprep_kernel(const float* __restrict__ Wp2, ushort_t* __restrict__ WtP,
                             const float* __restrict__ Wl2, ushort_t* __restrict__ WtL) {
  int i = blockIdx.x * blockDim.x + threadIdx.x;
  if (i < 16384) {
    int f = i >> 7, k = i & 127;
    WtP[i] = f2bf(Wp2[k * 128 + f]);
  } else if (i < 32768) {
    int j = i - 16384;
    int f = j >> 7, k = j & 127;
    WtL[j] = f2bf(Wl2[k * 128 + f]);
  }
}

// ---------------- hierarchical scan (CSR offsets) ----------------
__device__ inline void blocksum_dev(const int* cnt, int* bsum, int n, int b) {
  int t = threadIdx.x;
  int base = b * SCAN_CHUNK;
  int s = 0;
  for (int i = t; i < SCAN_CHUNK; i += 256) {
    int idx = base + i;
    if (idx < n) s += cnt[idx];
  }
  #pragma unroll
  for (int d = 32; d; d >>= 1) s += __shfl_down(s, d, 64);
  __shared__ int wt[4];
  int lane = t & 63, wid = t >> 6;
  if (lane == 0) wt[wid] = s;
  __syncthreads();
  if (t == 0) bsum[b] = wt[0] + wt[1] + wt[2] + wt[3];
}

__global__ __launch_bounds__(256) void blocksum2_kernel(
    const int* __restrict__ cntP, int nP, int nbP, int* __restrict__ bsumP,
    const int* __restrict__ cntL, int nL, int* __restrict__ bsumL) {
  int b = blockIdx.x;
  if (b < nbP) blocksum_dev(cntP, bsumP, nP, b);
  else blocksum_dev(cntL, bsumL, nL, b - nbP);
}

__device__ inline void exscan_small_dev(const int* bsum, int* boffs, int nb) {
  int t = threadIdx.x;
  int v = (t < nb) ? bsum[t] : 0;
  int lane = t & 63, wid = t >> 6;
  int inc = v;
  #pragma unroll
  for (int d = 1; d < 64; d <<= 1) {
    int u = __shfl_up(inc, d, 64);
    if (lane >= d) inc += u;
  }
  __shared__ int wt[16];
  if (lane == 63) wt[wid] = inc;
  __syncthreads();
  if (t < 16) {
    int w = wt[t];
    #pragma unroll
    for (int d = 1; d < 16; d <<= 1) {
      int u = __shfl_up(w, d, 64);
      if (t >= d) w += u;
    }
    wt[t] = w;
  }
  __syncthreads();
  int excl = (wid ? wt[wid - 1] : 0) + inc - v;
  if (t < nb) boffs[t] = excl;
  if (t == 0) boffs[nb] = wt[15];
}

__global__ __launch_bounds__(1024) void exscan2_kernel(const int* __restrict__ bsumP,
                                                       int* __restrict__ boffsP, int nbP,
                                                       const int* __restrict__ bsumL,
                                                       int* __restrict__ boffsL, int nbL) {
  if (blockIdx.x == 0) exscan_small_dev(bsumP, boffsP, nbP);
  else exscan_small_dev(bsumL, boffsL, nbL);
}

__device__ inline void scan_apply_dev(const int* cnt, const int* boffs, int* offs,
                                      int n, int nb, int b) {
  int t = threadIdx.x;
  int base = b * SCAN_CHUNK + t * 8;
  int v[8];
  int s = 0;
  #pragma unroll
  for (int j = 0; j < 8; ++j) {
    int idx = base + j;
    v[j] = (idx < n) ? cnt[idx] : 0;
    s += v[j];
  }
  int lane = t & 63, wid = t >> 6;
  int inc = s;
  #pragma unroll
  for (int d = 1; d < 64; d <<= 1) {
    int u = __shfl_up(inc, d, 64);
    if (lane >= d) inc += u;
  }
  __shared__ int wt[4];
  if (lane == 63) wt[wid] = inc;
  __syncthreads();
  int wadd = 0;
  for (int w = 0; w < wid; ++w) wadd += wt[w];
  int excl = boffs[b] + wadd + inc - s;
  #pragma unroll
  for (int j = 0; j < 8; ++j) {
    int idx = base + j;
    if (idx < n) offs[idx] = excl;
    excl += v[j];
  }
  if (b == 0 && t == 0) offs[n] = boffs[nb];
}

__global__ __launch_bounds__(256) void scan_apply2_kernel(
    const int* __restrict__ cntP, const int* __restrict__ boffsP, int* __restrict__ offsP,
    int nP, int nbP,
    const int* __restrict__ cntL, const int* __restrict__ boffsL, int* __restrict__ offsL,
    int nL, int nbL) {
  int b = blockIdx.x;
  if (b < nbP) scan_apply_dev(cntP, boffsP, offsP, nP, nbP, b);
  else scan_apply_dev(cntL, boffsL, offsL, nL, nbL, b - nbP);
}

// ---------------- R6 binning: count (LDS histogram, no global atomics) ------
__global__ __launch_bounds__(256) void bin_count_kernel(
    const int* __restrict__ dstP, int Ep, int nbkP, int nbeP, int* __restrict__ cntP,
    const int* __restrict__ dstL, int El, int nbkL, int* __restrict__ cntL) {
  __shared__ int hist[MAXBK];
  int j = blockIdx.x;
  const int* dst; int E, nbk; int* cnt;
  if (j < nbeP) { dst = dstP; E = Ep; nbk = nbkP; cnt = cntP; }
  else { j -= nbeP; dst = dstL; E = El; nbk = nbkL; cnt = cntL; }
  for (int i = threadIdx.x; i < nbk; i += 256) hist[i] = 0;
  __syncthreads();
  int e0 = j * EPB;
  for (int i = threadIdx.x; i < EPB; i += 256) {
    int e = e0 + i;
    if (e < E) atomicAdd(&hist[dst[e] >> BSHIFT], 1);
  }
  __syncthreads();
  for (int i = threadIdx.x; i < nbk; i += 256) cnt[(size_t)j * nbk + i] = hist[i];
}

// ---------------- R6 binning: per-bucket scan over blocks -> bases ----------
__global__ __launch_bounds__(256) void bin_scan_kernel(
    const int* __restrict__ offsP, int nbkP, int nbeP, int* __restrict__ mP,
    const int* __restrict__ offsL, int nbkL, int nbeL, int* __restrict__ mL) {
  int b = blockIdx.x;
  const int* offs; int nbk, nbe; int* m;
  if (b < nbkP) { offs = offsP; nbk = nbkP; nbe = nbeP; m = mP; }
  else { b -= nbkP; offs = offsL; nbk = nbkL; nbe = nbeL; m = mL; }
  int t = threadIdx.x, lane = t & 63, wid = t >> 6;
  int j0 = 2 * t;
  int v0 = (j0     < nbe) ? m[(size_t)j0       * nbk + b] : 0;
  int v1 = (j0 + 1 < nbe) ? m[(size_t)(j0 + 1) * nbk + b] : 0;
  int s = v0 + v1;
  int inc = s;
  #pragma unroll
  for (int d = 1; d < 64; d <<= 1) {
    int u = __shfl_up(inc, d, 64);
    if (lane >= d) inc += u;
  }
  __shared__ int wt[4];
  if (lane == 63) wt[wid] = inc;
  __syncthreads();
  int wadd = 0;
  for (int w = 0; w < wid; ++w) wadd += wt[w];
  int excl = offs[b << BSHIFT] + wadd + inc - s;
  if (j0     < nbe) m[(size_t)j0       * nbk + b] = excl;
  if (j0 + 1 < nbe) m[(size_t)(j0 + 1) * nbk + b] = excl + v0;
}

// ---------------- R6 binning: place pairs (LDS cursors only) ----------------
__global__ __launch_bounds__(256) void bin_place_kernel(
    const int* __restrict__ srcP, const int* __restrict__ dstP, int Ep, int nbkP, int nbeP,
    const int* __restrict__ baseP, int2* __restrict__ pairP,
    const int* __restrict__ srcL, const int* __restrict__ dstL, int El, int nbkL,
    const int* __restrict__ baseL, int2* __restrict__ pairL) {
  __shared__ int lbase[MAXBK];
  int j = blockIdx.x;
  const int* src; const int* dst; int E, nbk; const int* base_m; int2* pair;
  if (j < nbeP) { src = srcP; dst = dstP; E = Ep; nbk = nbkP; base_m = baseP; pair = pairP; }
  else { j -= nbeP; src = srcL; dst = dstL; E = El; nbk = nbkL; base_m = baseL; pair = pairL; }
  for (int i = threadIdx.x; i < nbk; i += 256)
    lbase[i] = base_m[(size_t)j * nbk + i];
  __syncthreads();
  int e0 = j * EPB;
  for (int i = threadIdx.x; i < EPB; i += 256) {
    int e = e0 + i;
    if (e < E) {
      int s = src[e], d = dst[e];
      int pos = atomicAdd(&lbase[d >> BSHIFT], 1);
      pair[pos] = make_int2(s, d);
    }
  }
}

// ---------------- scatter pass 2: one block per bucket, L2-local scatter -----
__global__ __launch_bounds__(256) void bucket_pass2_kernel(
    const int2* __restrict__ pairP, const int* __restrict__ offsP, int* __restrict__ curP,
    int* __restrict__ ssrcP, int nP, int nbkP,
    const int2* __restrict__ pairL, const int* __restrict__ offsL, int* __restrict__ curL,
    int* __restrict__ ssrcL, int nL) {
  int b = blockIdx.x;
  const int2* pair; const int* offs; int* cur; int* ssrc; int n;
  if (b < nbkP) { pair = pairP; offs = offsP; cur = curP; ssrc = ssrcP; n = nP; }
  else { b -= nbkP; pair = pairL; offs = offsL; cur = curL; ssrc = ssrcL; n = nL; }
  int lo = b << BSHIFT;
  int hi = lo + (1 << BSHIFT); if (hi > n) hi = n;
  int ebeg = offs[lo], eend = offs[hi];
  for (int i = ebeg + threadIdx.x; i < eend; i += 256) {
    int2 p = pair[i];
    int pos = offs[p.y] + atomicAdd(&cur[p.y], 1);
    ssrc[pos] = p.x;
  }
}

// ---------------- R7: fused layer-1 aggregate + transform + relu + dinv ------
// Gather the F-dim neighborhood sum (F<=32) into wave registers, then project
// to 128 features in-register: F shfl broadcasts x 2 FMA/lane against W1
// staged in LDS as float2 pairs {W[k][l], W[k][l+64]}. Stores h1' bf16
// (dinv[node] folded for the layer-2 pure-sum gather).
template<int F, int LPG>
__device__ inline void agg1t_dev(const float* __restrict__ x, const int* __restrict__ ssrc,
                                 const int* __restrict__ offs, const float* __restrict__ dinv,
                                 const float2* __restrict__ wp, const float2* __restrict__ bp,
                                 ushort_t* __restrict__ out, int node, int n) {
  if (node >= n) return;
  constexpr int G = 64 / LPG;  // edges in flight per wave
  int lane = threadIdx.x & 63;
  int grp = lane / LPG, l = lane % LPG;
  int beg = offs[node], end = offs[node + 1];
  float acc = 0.f;
  for (int b0 = beg; b0 < end; b0 += 64) {
    int m = end - b0; if (m > 64) m = 64;
    int sl = 0; float wl = 0.f;
    if (lane < m) { sl = ssrc[b0 + lane]; wl = dinv[sl]; }
    for (int k = 0; k < m; k += G) {
      int idx = k + grp;
      int s = __shfl(sl, idx, 64);
      float w = __shfl(wl, idx, 64);
      if (l < F) acc += x[(size_t)s * F + l] * w;
    }
  }
  // full reduce: every lane ends with the sum for feature (lane % LPG)
  #pragma unroll
  for (int d = LPG; d < 64; d <<= 1) acc += __shfl_xor(acc, d, 64);
  float di = dinv[node];
  if (l < F) acc = (acc + x[(size_t)node * F + l] * di) * di;  // GCN-normalized agg
  // project: lane handles features lane and lane+64
  float2 b2 = bp[lane];
  float s0 = b2.x, s1 = b2.y;
  #pragma unroll
  for (int k = 0; k < F; ++k) {
    float ak = __shfl(acc, k, 64);
    float2 w2 = wp[k * 64 + lane];
    s0 += ak * w2.x;
    s1 += ak * w2.y;
  }
  out[(size_t)node * 128 + lane]      = f2bf(fmaxf(s0, 0.f) * di);
  out[(size_t)node * 128 + 64 + lane] = f2bf(fmaxf(s1, 0.f) * di);
}

// 256 thr = 4 waves; each wave handles 4 consecutive nodes (16 nodes/block).
__global__ __launch_bounds__(256) void agg1t_both_kernel(
    const float* __restrict__ xP, const int* __restrict__ ssrcP,
    const int* __restrict__ offsP, const float* __restrict__ dinvP,
    const float* __restrict__ W1P, const float* __restrict__ b1P,
    ushort_t* __restrict__ outP, int nP, int nblkP,
    const float* __restrict__ xL, const int* __restrict__ ssrcL,
    const int* __restrict__ offsL, const float* __restrict__ dinvL,
    const float* __restrict__ W1L, const float* __restrict__ b1L,
    ushort_t* __restrict__ outL, int nL) {
  __shared__ float2 wp[23 * 64];
  __shared__ float2 bp[64];
  const int t = threadIdx.x;
  const int wv = t >> 6;
  const bool isP = (int)blockIdx.x < nblkP;
  const float* W1 = isP ? W1P : W1L;
  const float* b1 = isP ? b1P : b1L;
  const int F = isP ? 23 : 4;
  for (int i = t; i < F * 64; i += 256) {
    int k = i >> 6, l = i & 63;
    wp[i] = make_float2(W1[k * 128 + l], W1[k * 128 + 64 + l]);
  }
  if (t < 64) bp[t] = make_float2(b1[t], b1[t + 64]);
  __syncthreads();
  if (isP) {
    int node0 = (blockIdx.x * 4 + wv) * 4;
    #pragma unroll
    for (int i = 0; i < 4; ++i)
      agg1t_dev<23, 32>(xP, ssrcP, offsP, dinvP, wp, bp, outP, node0 + i, nP);
  } else {
    int node0 = ((blockIdx.x - nblkP) * 4 + wv) * 4;
    #pragma unroll
    for (int i = 0; i < 4; ++i)
      agg1t_dev<4, 4>(xL, ssrcL, offsL, dinvL, wp, bp, outL, node0 + i, nL);
  }
}

// ---------------- layer-2 aggregation: 4 edges/wave, 16B/lane uint4 ---------
// Table x holds h1' = h1 * dinv[src] (folded at layer-1 epilogue).
__device__ inline void agg128v_dev(const ushort_t* __restrict__ x, const int* __restrict__ ssrc,
                                   const int* __restrict__ offs, const float* __restrict__ dinv,
                                   ushort_t* __restrict__ out, int node, int n) {
  if (node >= n) return;
  int lane = threadIdx.x & 63;
  int g = lane >> 4, l = lane & 15;
  int beg = offs[node], end = offs[node + 1];
  float acc[8];
  #pragma unroll
  for (int j = 0; j < 8; ++j) acc[j] = 0.f;
  const uint4* x4 = (const uint4*)x;  // 16B units; row = 16 units (128 bf16)
  for (int b0 = beg; b0 < end; b0 += 64) {
    int m = end - b0; if (m > 64) m = 64;
    int sl = 0;
    if (lane < m) sl = ssrc[b0 + lane];
    for (int k = 0; k < m; k += 4) {
      int s = __shfl(sl, k + g, 64);
      if (k + g < m) {
        uint4 v = x4[(size_t)s * 16 + l];
        acc[0] += bf2f((ushort_t)(v.x & 0xffff)); acc[1] += bf2f((ushort_t)(v.x >> 16));
        acc[2] += bf2f((ushort_t)(v.y & 0xffff)); acc[3] += bf2f((ushort_t)(v.y >> 16));
        acc[4] += bf2f((ushort_t)(v.z & 0xffff)); acc[5] += bf2f((ushort_t)(v.z >> 16));
        acc[6] += bf2f((ushort_t)(v.w & 0xffff)); acc[7] += bf2f((ushort_t)(v.w >> 16));
      }
    }
  }
  #pragma unroll
  for (int j = 0; j < 8; ++j) {
    acc[j] += __shfl_xor(acc[j], 16, 64);
    acc[j] += __shfl_xor(acc[j], 32, 64);
  }
  if (g == 0) {
    uint4 v = x4[(size_t)node * 16 + l];
    float di = dinv[node];
    float r0 = (acc[0] + bf2f((ushort_t)(v.x & 0xffff))) * di;
    float r1 = (acc[1] + bf2f((ushort_t)(v.x >> 16)))   * di;
    float r2 = (acc[2] + bf2f((ushort_t)(v.y & 0xffff))) * di;
    float r3 = (acc[3] + bf2f((ushort_t)(v.y >> 16)))   * di;
    float r4 = (acc[4] + bf2f((ushort_t)(v.z & 0xffff))) * di;
    float r5 = (acc[5] + bf2f((ushort_t)(v.z >> 16)))   * di;
    float r6 = (acc[6] + bf2f((ushort_t)(v.w & 0xffff))) * di;
    float r7 = (acc[7] + bf2f((ushort_t)(v.w >> 16)))   * di;
    uint4 o;
    o.x = pack2bf(r0, r1); o.y = pack2bf(r2, r3);
    o.z = pack2bf(r4, r5); o.w = pack2bf(r6, r7);
    ((uint4*)out)[(size_t)node * 16 + l] = o;
  }
}

__global__ void agg2_both_kernel(const ushort_t* __restrict__ xP, const int* __restrict__ ssrcP,
                                 const int* __restrict__ offsP, const float* __restrict__ dinvP,
                                 ushort_t* __restrict__ outP, int nP, int nblkP,
                                 const ushort_t* __restrict__ xL, const int* __restrict__ ssrcL,
                                 const int* __restrict__ offsL, const float* __restrict__ dinvL,
                                 ushort_t* __restrict__ outL, int nL) {
  int wv = threadIdx.x >> 6;
  if ((int)blockIdx.x < nblkP)
    agg128v_dev(xP, ssrcP, offsP, dinvP, outP, blockIdx.x * 4 + wv, nP);
  else
    agg128v_dev(xL, ssrcL, offsL, dinvL, outL, (blockIdx.x - nblkP) * 4 + wv, nL);
}

// ---------------- layer-2 transform via MFMA bf16 ----------------
__global__ __launch_bounds__(512) void t2_mfma_kernel(
    const ushort_t* __restrict__ aggP, const ushort_t* __restrict__ WtP,
    const float* __restrict__ bP, float* __restrict__ h2P, int nP, int nblkP,
    const ushort_t* __restrict__ aggL, const ushort_t* __restrict__ WtL,
    const float* __restrict__ bL, float* __restrict__ h2L, int nL) {
  const ushort_t* agg; const ushort_t* Wt; const float* bias; float* out; int n, n0;
  if ((int)blockIdx.x < nblkP) {
    agg = aggP; Wt = WtP; bias = bP; out = h2P; n = nP; n0 = blockIdx.x * 128;
  } else {
    agg = aggL; Wt = WtL; bias = bL; out = h2L; n = nL;
    n0 = (blockIdx.x - nblkP) * 128;
  }
  __shared__ __align__(16) short sB[16384];  // 32KB: 128 nodes x 128 k bf16
  const int t = threadIdx.x;
  const int lane = t & 63;
  const int ws = t >> 6;

  #pragma unroll
  for (int c4 = 0; c4 < 4; ++c4) {
    int cidx = t + c4 * 512;
    int node = cidx >> 4, c = cidx & 15;
    uint4 v = make_uint4(0u, 0u, 0u, 0u);
    if (n0 + node < n) v = *(const uint4*)&agg[(size_t)(n0 + node) * 128 + c * 8];
    int off16 = (((node >> 4) * 4 + (c >> 2)) * 64) + (c & 3) * 16 + (node & 15);
    *(uint4*)&sB[off16 * 8] = v;
  }

  const int fs = ws * 16;
  bf16x8 a[4];
  #pragma unroll
  for (int kc = 0; kc < 4; ++kc)
    a[kc] = *(const bf16x8*)&Wt[(size_t)(fs + (lane & 15)) * 128 + kc * 32 + (lane >> 4) * 8];

  __syncthreads();

  f32x4 acc[8];
  #pragma unroll
  for (int g = 0; g < 8; ++g) acc[g] = (f32x4){0.f, 0.f, 0.f, 0.f};

  #pragma unroll
  for (int g = 0; g < 8; ++g) {
    #pragma unroll
    for (int kc = 0; kc < 4; ++kc) {
      bf16x8 b = *(const bf16x8*)&sB[(((g * 4 + kc) * 64) + lane) * 8];
      acc[g] = __builtin_amdgcn_mfma_f32_16x16x32_bf16(a[kc], b, acc[g], 0, 0, 0);
    }
  }

  const int f0 = fs + ((lane >> 4) << 2);
  float4 bv = *(const float4*)&bias[f0];
  #pragma unroll
  for (int g = 0; g < 8; ++g) {
    int node = n0 + g * 16 + (lane & 15);
    if (node < n) {
      float4 o;
      o.x = fmaxf(acc[g][0] + bv.x, 0.f);
      o.y = fmaxf(acc[g][1] + bv.y, 0.f);
      o.z = fmaxf(acc[g][2] + bv.z, 0.f);
      o.w = fmaxf(acc[g][3] + bv.w, 0.f);
      *(float4*)&out[(size_t)node * 128 + f0] = o;
    }
  }
}

// ---------------- segmented mean-pool (both graphs) ----------------
__device__ inline void pool_dev(const float* __restrict__ h, const int* __restrict__ start,
                                float* __restrict__ mean, int g) {
  int t = threadIdx.x;
  int f = t & 127, r = t >> 7;
  int beg = start[g], end = start[g + 1];
  float acc = 0.f;
  for (int i = beg + r; i < end; i += 4)
    acc += h[(size_t)i * 128 + f];
  __shared__ float red[4][128];
  red[r][f] = acc;
  __syncthreads();
  if (r == 0) {
    float s = red[0][f] + red[1][f] + red[2][f] + red[3][f];
    float c = (float)(end - beg);
    mean[(size_t)g * 128 + f] = s / fmaxf(c, 1.f);
  }
}

__global__ __launch_bounds__(512) void pool_both_kernel(
    const float* __restrict__ hP, const int* __restrict__ startP, float* __restrict__ meanP,
    const float* __restrict__ hL, const int* __restrict__ startL, float* __restrict__ meanL,
    int G) {
  int g = blockIdx.x;
  if (g < G) pool_dev(hP, startP, meanP, g);
  else pool_dev(hL, startL, meanL, g - G);
}

// ---------------- final FC + 3 heads ----------------
__global__ __launch_bounds__(128) void fc_heads_kernel(
    const float* __restrict__ pe, const float* __restrict__ le,
    const float* __restrict__ Wfc, const float* __restrict__ bfc,
    const float* __restrict__ Wpkd, const float* __restrict__ bpkd,
    const float* __restrict__ Wpki, const float* __restrict__ bpki,
    const float* __restrict__ Wba, const float* __restrict__ bba,
    float* __restrict__ out, int G) {
  int g = blockIdx.x, f = threadIdx.x;
  __shared__ float comb[256];
  __shared__ float cbuf[128];
  comb[f]       = pe[(size_t)g * 128 + f];
  comb[128 + f] = le[(size_t)g * 128 + f];
  __syncthreads();
  float acc = bfc[f];
  for (int k = 0; k < 256; ++k) acc += comb[k] * Wfc[(size_t)k * 128 + f];
  cbuf[f] = fmaxf(acc, 0.f);
  __syncthreads();
  if (f < 64) {
    const float* Wh[3] = {Wpkd, Wpki, Wba};
    const float* bh[3] = {bpkd, bpki, bba};
    #pragma unroll
    for (int hd = 0; hd < 3; ++hd) {
      float v = cbuf[f] * Wh[hd][f] + cbuf[f + 64] * Wh[hd][f + 64];
      #pragma unroll
      for (int d = 32; d; d >>= 1) v += __shfl_xor(v, d, 64);
      if (f == 0) out[(size_t)hd * G + g] = v + bh[hd][0];
    }
  }
}

// ============================================================================
static inline size_t alignUp(size_t x, size_t a) { return (x + a - 1) / a * a; }

extern "C" void kernel_launch(void* const* d_in, const int* in_sizes, int n_in,
                              void* d_out, int out_size, void* d_ws, size_t ws_size,
                              hipStream_t stream) {
  const float* px     = (const float*)d_in[0];
  const int*   pei    = (const int*)d_in[1];
  const int*   pbatch = (const int*)d_in[2];
  const float* lx     = (const float*)d_in[3];
  const int*   lei    = (const int*)d_in[4];
  const int*   lbatch = (const int*)d_in[5];
  const float* Wp1 = (const float*)d_in[7],  *bp1 = (const float*)d_in[8];
  const float* Wp2 = (const float*)d_in[9],  *bp2 = (const float*)d_in[10];
  const float* Wl1 = (const float*)d_in[11], *bl1 = (const float*)d_in[12];
  const float* Wl2 = (const float*)d_in[13], *bl2 = (const float*)d_in[14];
  const float* Wfc = (const float*)d_in[15], *bfc = (const float*)d_in[16];
  const float* Wpkd = (const float*)d_in[17], *bpkd = (const float*)d_in[18];
  const float* Wpki = (const float*)d_in[19], *bpki = (const float*)d_in[20];
  const float* Wba  = (const float*)d_in[21], *bba  = (const float*)d_in[22];
  float* out = (float*)d_out;

  const int Np = in_sizes[0] / 23, Ep = in_sizes[1] / 2;
  const int Nl = in_sizes[3] / 4,  El = in_sizes[4] / 2;
  const int G  = out_size / 3;
  const int nb_p = (Np + SCAN_CHUNK - 1) / SCAN_CHUNK;
  const int nb_l = (Nl + SCAN_CHUNK - 1) / SCAN_CHUNK;
  const int nbk_p = (Np + (1 << BSHIFT) - 1) >> BSHIFT;   // scatter buckets
  const int nbk_l = (Nl + (1 << BSHIFT) - 1) >> BSHIFT;
  const int nbe_p = (Ep + EPB - 1) / EPB;                 // binning blocks
  const int nbe_l = (El + EPB - 1) / EPB;

  // ---- workspace layout ----
  char* base = (char*)d_ws;
  size_t off = 0;
  auto alloc = [&](size_t bytes) -> void* {
    void* p = base + off;
    off = alignUp(off + bytes, 256);
    return p;
  };
  size_t zero_beg = off;
  int*   degcnt_p = (int*)alloc((size_t)Np * 4);
  int*   cursor_p = (int*)alloc((size_t)Np * 4);
  int*   degcnt_l = (int*)alloc((size_t)Nl * 4);
  int*   cursor_l = (int*)alloc((size_t)Nl * 4);
  size_t zero_end = off;
  int*   offs_p  = (int*)alloc((size_t)(Np + 1) * 4);
  int*   offs_l  = (int*)alloc((size_t)(Nl + 1) * 4);
  int*   bsum_p  = (int*)alloc((size_t)nb_p * 4);
  int*   boffs_p = (int*)alloc((size_t)(nb_p + 1) * 4);
  int*   bsum_l  = (int*)alloc((size_t)nb_l * 4);
  int*   boffs_l = (int*)alloc((size_t)(nb_l + 1) * 4);
  int*   start_p = (int*)alloc((size_t)(G + 1) * 4);
  int*   start_l = (int*)alloc((size_t)(G + 1) * 4);
  float* dinv_p  = (float*)alloc((size_t)Np * 4);
  float* dinv_l  = (float*)alloc((size_t)Nl * 4);
  int*   ssrc_p  = (int*)alloc((size_t)Ep * 4);
  int*   ssrc_l  = (int*)alloc((size_t)El * 4);
  int2*  pair_p  = (int2*)alloc((size_t)Ep * 8);
  int2*  pair_l  = (int2*)alloc((size_t)El * 8);
  int*   cmat_p  = (int*)alloc((size_t)nbe_p * nbk_p * 4);  // [block][bucket]
  int*   cmat_l  = (int*)alloc((size_t)nbe_l * nbk_l * 4);
  float* pe_mean = (float*)alloc((size_t)G * 128 * 4);
  float* le_mean = (float*)alloc((size_t)G * 128 * 4);
  ushort_t* wt2_p = (ushort_t*)alloc((size_t)16384 * 2);
  ushort_t* wt2_l = (ushort_t*)alloc((size_t)16384 * 2);
  ushort_t* h1_p   = (ushort_t*)alloc((size_t)Np * 128 * 2);  // bf16 h1'=h1*dinv
  ushort_t* agg2_p = (ushort_t*)alloc((size_t)Np * 128 * 2);  // bf16
  float*    h2_p   = (float*)alloc((size_t)Np * 128 * 4);
  ushort_t* h1_l   = (ushort_t*)alloc((size_t)Nl * 128 * 2);  // bf16 h1'=h1*dinv
  ushort_t* agg2_l = (ushort_t*)alloc((size_t)Nl * 128 * 2);  // bf16
  float*    h2_l   = (float*)alloc((size_t)Nl * 128 * 4);
  if (off > ws_size) return;

  hipMemsetAsync(base + zero_beg, 0, zero_end - zero_beg, stream);

  const int* psrc = pei;
  const int* pdst = pei + Ep;
  const int* lsrc = lei;
  const int* ldst = lei + El;

  // ---- weight prep (independent) ----
  wprep_kernel<<<128, 256, 0, stream>>>(Wp2, wt2_p, Wl2, wt2_l);

  // ---- CSR build + per-node prep ----
  count_deg2_kernel<<<(Ep + El + 255) / 256, 256, 0, stream>>>(pdst, Ep, degcnt_p,
                                                               ldst, El, degcnt_l);
  node_prep_kernel<<<(Np + Nl + 255) / 256, 256, 0, stream>>>(
      degcnt_p, dinv_p, pbatch, start_p, Np,
      degcnt_l, dinv_l, lbatch, start_l, Nl, G);
  blocksum2_kernel<<<nb_p + nb_l, 256, 0, stream>>>(degcnt_p, Np, nb_p, bsum_p,
                                                    degcnt_l, Nl, bsum_l);
  exscan2_kernel<<<2, 1024, 0, stream>>>(bsum_p, boffs_p, nb_p, bsum_l, boffs_l, nb_l);
  scan_apply2_kernel<<<nb_p + nb_l, 256, 0, stream>>>(degcnt_p, boffs_p, offs_p, Np, nb_p,
                                                      degcnt_l, boffs_l, offs_l, Nl, nb_l);

  // ---- R6 binning (zero global atomics) + bucket-local scatter ----
  bin_count_kernel<<<nbe_p + nbe_l, 256, 0, stream>>>(
      pdst, Ep, nbk_p, nbe_p, cmat_p,
      ldst, El, nbk_l, cmat_l);
  bin_scan_kernel<<<nbk_p + nbk_l, 256, 0, stream>>>(
      offs_p, nbk_p, nbe_p, cmat_p,
      offs_l, nbk_l, nbe_l, cmat_l);
  bin_place_kernel<<<nbe_p + nbe_l, 256, 0, stream>>>(
      psrc, pdst, Ep, nbk_p, nbe_p, cmat_p, pair_p,
      lsrc, ldst, El, nbk_l, cmat_l, pair_l);
  bucket_pass2_kernel<<<nbk_p + nbk_l, 256, 0, stream>>>(
      pair_p, offs_p, cursor_p, ssrc_p, Np, nbk_p,
      pair_l, offs_l, cursor_l, ssrc_l, Nl);

  // ---- GNN layer 1: fused aggregate+transform (R7) ----
  const int a1blkP = (Np + 15) / 16, a1blkL = (Nl + 15) / 16;
  agg1t_both_kernel<<<a1blkP + a1blkL, 256, 0, stream>>>(
      px, ssrc_p, offs_p, dinv_p, Wp1, bp1, h1_p, Np, a1blkP,
      lx, ssrc_l, offs_l, dinv_l, Wl1, bl1, h1_l, Nl);

  // ---- GNN layer 2 (both graphs fused) ----
  const int ablkP = (Np + 3) / 4, ablkL = (Nl + 3) / 4;
  agg2_both_kernel<<<ablkP + ablkL, 256, 0, stream>>>(
      h1_p, ssrc_p, offs_p, dinv_p, agg2_p, Np, ablkP,
      h1_l, ssrc_l, offs_l, dinv_l, agg2_l, Nl);
  const int mblkP = (Np + 127) / 128, mblkL = (Nl + 127) / 128;
  t2_mfma_kernel<<<mblkP + mblkL, 512, 0, stream>>>(
      agg2_p, wt2_p, bp2, h2_p, Np, mblkP,
      agg2_l, wt2_l, bl2, h2_l, Nl);

  // ---- pool + FC/heads ----
  pool_both_kernel<<<2 * G, 512, 0, stream>>>(h2_p, start_p, pe_mean,
                                              h2_l, start_l, le_mean, G);
  fc_heads_kernel<<<G, 128, 0, stream>>>(pe_mean, le_mean, Wfc, bfc,
                                         Wpkd, bpkd, Wpki, bpki, Wba, bba, out, G);
}

// Round 9
// 342.504 us; speedup vs baseline: 2.8945x; 1.0629x over previous
//
#include <hip/hip_runtime.h>

// ============================================================================
// ProteinLigandGNN: 2x GCNConv (protein), 2x GCNConv (ligand), mean-pool,
// FC + 3 heads.
//
// GCNConv: out = D^-1/2 (A+I) D^-1/2 (X W) + b  ==  (D^-1/2 (A+I) D^-1/2 X) W + b
// Aggregate FIRST (narrow feature space when possible), then transform.
// R3: protein h1 bf16; fused P+L launches.
// R4: layer-2 transform via MFMA bf16; agg2/W2 bf16.
// R5: agg2 -> 4 edges/wave, 16B/lane uint4 gather; dinv folded into h1' table.
// R6: zero-global-atomic counting-sort binning (lesson: contended global
//     atomics serialize at ~146ns/op cross-XCD RMW).
// R7: transform1 fused into agg1 (removes 80us kernel + intermediate).
// R8: protein x-table -> bf16 padded to 32 elems = ONE 64B line per row
//     (was 92B f32 rows straddling 2 lines: 125MB FETCH on agg1t). Gather
//     restructured to 4 edges in flight x 16 lanes x uint (2 bf16).
// ============================================================================

typedef unsigned short ushort_t;
typedef short bf16x8 __attribute__((ext_vector_type(8)));
typedef float f32x4 __attribute__((ext_vector_type(4)));

#define SCAN_CHUNK 2048
#define BSHIFT 8        // 256 dst nodes per scatter bucket
#define EPB 4096        // edges per binning block
#define MAXBK 1024      // max buckets (nodes <= 256k)

static __device__ inline ushort_t f2bf(float f) {  // RNE f32->bf16
  unsigned u = __float_as_uint(f);
  unsigned r = (u + 0x7FFFu + ((u >> 16) & 1u)) >> 16;
  return (ushort_t)r;
}
static __device__ inline float bf2f(ushort_t b) {
  return __uint_as_float((unsigned)b << 16);
}
static __device__ inline unsigned pack2bf(float lo, float hi) {
  return (unsigned)f2bf(lo) | ((unsigned)f2bf(hi) << 16);
}

// ---------------- fused degree count (both graphs) ----------------
__global__ void count_deg2_kernel(const int* __restrict__ dstP, int Ep, int* __restrict__ degP,
                                  const int* __restrict__ dstL, int El, int* __restrict__ degL) {
  int e = blockIdx.x * blockDim.x + threadIdx.x;
  if (e < Ep) atomicAdd(&degP[dstP[e]], 1);
  else if (e < Ep + El) atomicAdd(&degL[dstL[e - Ep]], 1);
}

// ---------------- fused per-node prep: dinv + segment starts ----------------
__device__ inline void node_prep_dev(const int* deg, float* dinv, const int* batch,
                                     int* start, int i, int n, int G) {
  dinv[i] = rsqrtf((float)(deg[i] + 1));
  int b = batch[i];
  if (i == 0) { for (int g = 0; g <= b; ++g) start[g] = 0; }
  else { int pb = batch[i - 1]; for (int g = pb + 1; g <= b; ++g) start[g] = i; }
  if (i == n - 1) { for (int g = b + 1; g <= G; ++g) start[g] = n; }
}

__global__ void node_prep_kernel(const int* __restrict__ degP, float* __restrict__ dinvP,
                                 const int* __restrict__ batchP, int* __restrict__ startP, int nP,
                                 const int* __restrict__ degL, float* __restrict__ dinvL,
                                 const int* __restrict__ batchL, int* __restrict__ startL, int nL,
                                 int G) {
  int i = blockIdx.x * blockDim.x + threadIdx.x;
  if (i < nP) node_prep_dev(degP, dinvP, batchP, startP, i, nP, G);
  int j = i - nP;
  if (j >= 0 && j < nL) node_prep_dev(degL, dinvL, batchL, startL, j, nL, G);
}

// ---------------- weight prep + protein-x bf16 pad-32 conversion ------------
// i < 16384:          WtP (W2^T bf16, protein)
// i < 32768:          WtL (W2^T bf16, ligand)
// i < 32768 + Np*16:  xbf_p row conversion (uint = 2 bf16 per thread)
__global__ void wprep_kernel(const float* __restrict__ Wp2, ushort_t* __restrict__ WtP,
                             const float* __restrict__ Wl2, ushort_t* __restrict__ WtL,
                             const float* __restrict__ px, unsigned* __restrict__ xbfP, int Np) {
  int i = blockIdx.x * blockDim.x + threadIdx.x;
  if (i < 16384) {
    int f = i >> 7, k = i & 127;
    WtP[i] = f2bf(Wp2[k * 128 + f]);
  } else if (i < 32768) {
    int j = i - 16384;
    int f = j >> 7, k = j & 127;
    WtL[j] = f2bf(Wl2[k * 128 + f]);
  } else {
    int j = i - 32768;
    if (j < Np * 16) {
      int row = j >> 4, c2 = (j & 15) * 2;   // features c2, c2+1
      float lo = (c2     < 23) ? px[(size_t)row * 23 + c2]     : 0.f;
      float hi = (c2 + 1 < 23) ? px[(size_t)row * 23 + c2 + 1] : 0.f;
      xbfP[j] = pack2bf(lo, hi);
    }
  }
}

// ---------------- hierarchical scan (CSR offsets) ----------------
__device__ inline void blocksum_dev(const int* cnt, int* bsum, int n, int b) {
  int t = threadIdx.x;
  int base = b * SCAN_CHUNK;
  int s = 0;
  for (int i = t; i < SCAN_CHUNK; i += 256) {
    int idx = base + i;
    if (idx < n) s += cnt[idx];
  }
  #pragma unroll
  for (int d = 32; d; d >>= 1) s += __shfl_down(s, d, 64);
  __shared__ int wt[4];
  int lane = t & 63, wid = t >> 6;
  if (lane == 0) wt[wid] = s;
  __syncthreads();
  if (t == 0) bsum[b] = wt[0] + wt[1] + wt[2] + wt[3];
}

__global__ __launch_bounds__(256) void blocksum2_kernel(
    const int* __restrict__ cntP, int nP, int nbP, int* __restrict__ bsumP,
    const int* __restrict__ cntL, int nL, int* __restrict__ bsumL) {
  int b = blockIdx.x;
  if (b < nbP) blocksum_dev(cntP, bsumP, nP, b);
  else blocksum_dev(cntL, bsumL, nL, b - nbP);
}

__device__ inline void exscan_small_dev(const int* bsum, int* boffs, int nb) {
  int t = threadIdx.x;
  int v = (t < nb) ? bsum[t] : 0;
  int lane = t & 63, wid = t >> 6;
  int inc = v;
  #pragma unroll
  for (int d = 1; d < 64; d <<= 1) {
    int u = __shfl_up(inc, d, 64);
    if (lane >= d) inc += u;
  }
  __shared__ int wt[16];
  if (lane == 63) wt[wid] = inc;
  __syncthreads();
  if (t < 16) {
    int w = wt[t];
    #pragma unroll
    for (int d = 1; d < 16; d <<= 1) {
      int u = __shfl_up(w, d, 64);
      if (t >= d) w += u;
    }
    wt[t] = w;
  }
  __syncthreads();
  int excl = (wid ? wt[wid - 1] : 0) + inc - v;
  if (t < nb) boffs[t] = excl;
  if (t == 0) boffs[nb] = wt[15];
}

__global__ __launch_bounds__(1024) void exscan2_kernel(const int* __restrict__ bsumP,
                                                       int* __restrict__ boffsP, int nbP,
                                                       const int* __restrict__ bsumL,
                                                       int* __restrict__ boffsL, int nbL) {
  if (blockIdx.x == 0) exscan_small_dev(bsumP, boffsP, nbP);
  else exscan_small_dev(bsumL, boffsL, nbL);
}

__device__ inline void scan_apply_dev(const int* cnt, const int* boffs, int* offs,
                                      int n, int nb, int b) {
  int t = threadIdx.x;
  int base = b * SCAN_CHUNK + t * 8;
  int v[8];
  int s = 0;
  #pragma unroll
  for (int j = 0; j < 8; ++j) {
    int idx = base + j;
    v[j] = (idx < n) ? cnt[idx] : 0;
    s += v[j];
  }
  int lane = t & 63, wid = t >> 6;
  int inc = s;
  #pragma unroll
  for (int d = 1; d < 64; d <<= 1) {
    int u = __shfl_up(inc, d, 64);
    if (lane >= d) inc += u;
  }
  __shared__ int wt[4];
  if (lane == 63) wt[wid] = inc;
  __syncthreads();
  int wadd = 0;
  for (int w = 0; w < wid; ++w) wadd += wt[w];
  int excl = boffs[b] + wadd + inc - s;
  #pragma unroll
  for (int j = 0; j < 8; ++j) {
    int idx = base + j;
    if (idx < n) offs[idx] = excl;
    excl += v[j];
  }
  if (b == 0 && t == 0) offs[n] = boffs[nb];
}

__global__ __launch_bounds__(256) void scan_apply2_kernel(
    const int* __restrict__ cntP, const int* __restrict__ boffsP, int* __restrict__ offsP,
    int nP, int nbP,
    const int* __restrict__ cntL, const int* __restrict__ boffsL, int* __restrict__ offsL,
    int nL, int nbL) {
  int b = blockIdx.x;
  if (b < nbP) scan_apply_dev(cntP, boffsP, offsP, nP, nbP, b);
  else scan_apply_dev(cntL, boffsL, offsL, nL, nbL, b - nbP);
}

// ---------------- R6 binning: count (LDS histogram, no global atomics) ------
__global__ __launch_bounds__(256) void bin_count_kernel(
    const int* __restrict__ dstP, int Ep, int nbkP, int nbeP, int* __restrict__ cntP,
    const int* __restrict__ dstL, int El, int nbkL, int* __restrict__ cntL) {
  __shared__ int hist[MAXBK];
  int j = blockIdx.x;
  const int* dst; int E, nbk; int* cnt;
  if (j < nbeP) { dst = dstP; E = Ep; nbk = nbkP; cnt = cntP; }
  else { j -= nbeP; dst = dstL; E = El; nbk = nbkL; cnt = cntL; }
  for (int i = threadIdx.x; i < nbk; i += 256) hist[i] = 0;
  __syncthreads();
  int e0 = j * EPB;
  for (int i = threadIdx.x; i < EPB; i += 256) {
    int e = e0 + i;
    if (e < E) atomicAdd(&hist[dst[e] >> BSHIFT], 1);
  }
  __syncthreads();
  for (int i = threadIdx.x; i < nbk; i += 256) cnt[(size_t)j * nbk + i] = hist[i];
}

// ---------------- R6 binning: per-bucket scan over blocks -> bases ----------
__global__ __launch_bounds__(256) void bin_scan_kernel(
    const int* __restrict__ offsP, int nbkP, int nbeP, int* __restrict__ mP,
    const int* __restrict__ offsL, int nbkL, int nbeL, int* __restrict__ mL) {
  int b = blockIdx.x;
  const int* offs; int nbk, nbe; int* m;
  if (b < nbkP) { offs = offsP; nbk = nbkP; nbe = nbeP; m = mP; }
  else { b -= nbkP; offs = offsL; nbk = nbkL; nbe = nbeL; m = mL; }
  int t = threadIdx.x, lane = t & 63, wid = t >> 6;
  int j0 = 2 * t;
  int v0 = (j0     < nbe) ? m[(size_t)j0       * nbk + b] : 0;
  int v1 = (j0 + 1 < nbe) ? m[(size_t)(j0 + 1) * nbk + b] : 0;
  int s = v0 + v1;
  int inc = s;
  #pragma unroll
  for (int d = 1; d < 64; d <<= 1) {
    int u = __shfl_up(inc, d, 64);
    if (lane >= d) inc += u;
  }
  __shared__ int wt[4];
  if (lane == 63) wt[wid] = inc;
  __syncthreads();
  int wadd = 0;
  for (int w = 0; w < wid; ++w) wadd += wt[w];
  int excl = offs[b << BSHIFT] + wadd + inc - s;
  if (j0     < nbe) m[(size_t)j0       * nbk + b] = excl;
  if (j0 + 1 < nbe) m[(size_t)(j0 + 1) * nbk + b] = excl + v0;
}

// ---------------- R6 binning: place pairs (LDS cursors only) ----------------
__global__ __launch_bounds__(256) void bin_place_kernel(
    const int* __restrict__ srcP, const int* __restrict__ dstP, int Ep, int nbkP, int nbeP,
    const int* __restrict__ baseP, int2* __restrict__ pairP,
    const int* __restrict__ srcL, const int* __restrict__ dstL, int El, int nbkL,
    const int* __restrict__ baseL, int2* __restrict__ pairL) {
  __shared__ int lbase[MAXBK];
  int j = blockIdx.x;
  const int* src; const int* dst; int E, nbk; const int* base_m; int2* pair;
  if (j < nbeP) { src = srcP; dst = dstP; E = Ep; nbk = nbkP; base_m = baseP; pair = pairP; }
  else { j -= nbeP; src = srcL; dst = dstL; E = El; nbk = nbkL; base_m = baseL; pair = pairL; }
  for (int i = threadIdx.x; i < nbk; i += 256)
    lbase[i] = base_m[(size_t)j * nbk + i];
  __syncthreads();
  int e0 = j * EPB;
  for (int i = threadIdx.x; i < EPB; i += 256) {
    int e = e0 + i;
    if (e < E) {
      int s = src[e], d = dst[e];
      int pos = atomicAdd(&lbase[d >> BSHIFT], 1);
      pair[pos] = make_int2(s, d);
    }
  }
}

// ---------------- scatter pass 2: one block per bucket, L2-local scatter -----
__global__ __launch_bounds__(256) void bucket_pass2_kernel(
    const int2* __restrict__ pairP, const int* __restrict__ offsP, int* __restrict__ curP,
    int* __restrict__ ssrcP, int nP, int nbkP,
    const int2* __restrict__ pairL, const int* __restrict__ offsL, int* __restrict__ curL,
    int* __restrict__ ssrcL, int nL) {
  int b = blockIdx.x;
  const int2* pair; const int* offs; int* cur; int* ssrc; int n;
  if (b < nbkP) { pair = pairP; offs = offsP; cur = curP; ssrc = ssrcP; n = nP; }
  else { b -= nbkP; pair = pairL; offs = offsL; cur = curL; ssrc = ssrcL; n = nL; }
  int lo = b << BSHIFT;
  int hi = lo + (1 << BSHIFT); if (hi > n) hi = n;
  int ebeg = offs[lo], eend = offs[hi];
  for (int i = ebeg + threadIdx.x; i < eend; i += 256) {
    int2 p = pair[i];
    int pos = offs[p.y] + atomicAdd(&cur[p.y], 1);
    ssrc[pos] = p.x;
  }
}

// ---------------- R8: protein layer-1 fused agg+transform, bf16 line-gather --
// x rows are 32 bf16 = one 64B line. 4 edges in flight per wave: 16-lane
// group g reads edge (k+g)'s row as 16x uint (2 bf16 each). Lane l holds
// features {2l, 2l+1}. Projection: 23 shfl broadcasts x 2 FMA vs LDS W1.
__device__ inline void agg1t_bf_dev(const unsigned* __restrict__ x, const int* __restrict__ ssrc,
                                    const int* __restrict__ offs, const float* __restrict__ dinv,
                                    const float2* __restrict__ wp, const float2* __restrict__ bp,
                                    ushort_t* __restrict__ out, int node, int n) {
  if (node >= n) return;
  int lane = threadIdx.x & 63;
  int g = lane >> 4, l = lane & 15;
  int beg = offs[node], end = offs[node + 1];
  float a0 = 0.f, a1 = 0.f;
  for (int b0 = beg; b0 < end; b0 += 64) {
    int m = end - b0; if (m > 64) m = 64;
    int sl = 0; float wl = 0.f;
    if (lane < m) { sl = ssrc[b0 + lane]; wl = dinv[sl]; }
    for (int k = 0; k < m; k += 4) {
      int idx = k + g;                       // <= 63; wl==0 beyond m
      int s = __shfl(sl, idx, 64);
      float w = __shfl(wl, idx, 64);
      unsigned u = x[(size_t)s * 16 + l];    // 16 lanes x 4B = the 64B row
      a0 += bf2f((ushort_t)(u & 0xffff)) * w;
      a1 += bf2f((ushort_t)(u >> 16)) * w;
    }
  }
  a0 += __shfl_xor(a0, 16, 64); a0 += __shfl_xor(a0, 32, 64);
  a1 += __shfl_xor(a1, 16, 64); a1 += __shfl_xor(a1, 32, 64);
  float di = dinv[node];
  unsigned u = x[(size_t)node * 16 + l];
  a0 = (a0 + bf2f((ushort_t)(u & 0xffff)) * di) * di;
  a1 = (a1 + bf2f((ushort_t)(u >> 16)) * di) * di;
  // project: lane handles output features lane and lane+64
  float2 b2 = bp[lane];
  float s0 = b2.x, s1 = b2.y;
  #pragma unroll
  for (int k = 0; k < 23; ++k) {
    float ak = __shfl((k & 1) ? a1 : a0, k >> 1, 64);
    float2 w2 = wp[k * 64 + lane];
    s0 += ak * w2.x;
    s1 += ak * w2.y;
  }
  out[(size_t)node * 128 + lane]      = f2bf(fmaxf(s0, 0.f) * di);
  out[(size_t)node * 128 + 64 + lane] = f2bf(fmaxf(s1, 0.f) * di);
}

// ---------------- ligand layer-1 (f32 table, L2-resident) ----------------
template<int F, int LPG>
__device__ inline void agg1t_dev(const float* __restrict__ x, const int* __restrict__ ssrc,
                                 const int* __restrict__ offs, const float* __restrict__ dinv,
                                 const float2* __restrict__ wp, const float2* __restrict__ bp,
                                 ushort_t* __restrict__ out, int node, int n) {
  if (node >= n) return;
  constexpr int G = 64 / LPG;
  int lane = threadIdx.x & 63;
  int grp = lane / LPG, l = lane % LPG;
  int beg = offs[node], end = offs[node + 1];
  float acc = 0.f;
  for (int b0 = beg; b0 < end; b0 += 64) {
    int m = end - b0; if (m > 64) m = 64;
    int sl = 0; float wl = 0.f;
    if (lane < m) { sl = ssrc[b0 + lane]; wl = dinv[sl]; }
    for (int k = 0; k < m; k += G) {
      int idx = k + grp;
      int s = __shfl(sl, idx, 64);
      float w = __shfl(wl, idx, 64);
      if (l < F) acc += x[(size_t)s * F + l] * w;
    }
  }
  #pragma unroll
  for (int d = LPG; d < 64; d <<= 1) acc += __shfl_xor(acc, d, 64);
  float di = dinv[node];
  if (l < F) acc = (acc + x[(size_t)node * F + l] * di) * di;
  float2 b2 = bp[lane];
  float s0 = b2.x, s1 = b2.y;
  #pragma unroll
  for (int k = 0; k < F; ++k) {
    float ak = __shfl(acc, k, 64);
    float2 w2 = wp[k * 64 + lane];
    s0 += ak * w2.x;
    s1 += ak * w2.y;
  }
  out[(size_t)node * 128 + lane]      = f2bf(fmaxf(s0, 0.f) * di);
  out[(size_t)node * 128 + 64 + lane] = f2bf(fmaxf(s1, 0.f) * di);
}

// 256 thr = 4 waves; each wave handles 4 consecutive nodes (16 nodes/block).
__global__ __launch_bounds__(256) void agg1t_both_kernel(
    const unsigned* __restrict__ xbfP, const int* __restrict__ ssrcP,
    const int* __restrict__ offsP, const float* __restrict__ dinvP,
    const float* __restrict__ W1P, const float* __restrict__ b1P,
    ushort_t* __restrict__ outP, int nP, int nblkP,
    const float* __restrict__ xL, const int* __restrict__ ssrcL,
    const int* __restrict__ offsL, const float* __restrict__ dinvL,
    const float* __restrict__ W1L, const float* __restrict__ b1L,
    ushort_t* __restrict__ outL, int nL) {
  __shared__ float2 wp[23 * 64];
  __shared__ float2 bp[64];
  const int t = threadIdx.x;
  const int wv = t >> 6;
  const bool isP = (int)blockIdx.x < nblkP;
  const float* W1 = isP ? W1P : W1L;
  const float* b1 = isP ? b1P : b1L;
  const int F = isP ? 23 : 4;
  for (int i = t; i < F * 64; i += 256) {
    int k = i >> 6, l = i & 63;
    wp[i] = make_float2(W1[k * 128 + l], W1[k * 128 + 64 + l]);
  }
  if (t < 64) bp[t] = make_float2(b1[t], b1[t + 64]);
  __syncthreads();
  if (isP) {
    int node0 = (blockIdx.x * 4 + wv) * 4;
    #pragma unroll
    for (int i = 0; i < 4; ++i)
      agg1t_bf_dev(xbfP, ssrcP, offsP, dinvP, wp, bp, outP, node0 + i, nP);
  } else {
    int node0 = ((blockIdx.x - nblkP) * 4 + wv) * 4;
    #pragma unroll
    for (int i = 0; i < 4; ++i)
      agg1t_dev<4, 4>(xL, ssrcL, offsL, dinvL, wp, bp, outL, node0 + i, nL);
  }
}

// ---------------- layer-2 aggregation: 4 edges/wave, 16B/lane uint4 ---------
// Table x holds h1' = h1 * dinv[src] (folded at layer-1 epilogue).
__device__ inline void agg128v_dev(const ushort_t* __restrict__ x, const int* __restrict__ ssrc,
                                   const int* __restrict__ offs, const float* __restrict__ dinv,
                                   ushort_t* __restrict__ out, int node, int n) {
  if (node >= n) return;
  int lane = threadIdx.x & 63;
  int g = lane >> 4, l = lane & 15;
  int beg = offs[node], end = offs[node + 1];
  float acc[8];
  #pragma unroll
  for (int j = 0; j < 8; ++j) acc[j] = 0.f;
  const uint4* x4 = (const uint4*)x;  // 16B units; row = 16 units (128 bf16)
  for (int b0 = beg; b0 < end; b0 += 64) {
    int m = end - b0; if (m > 64) m = 64;
    int sl = 0;
    if (lane < m) sl = ssrc[b0 + lane];
    for (int k = 0; k < m; k += 4) {
      int s = __shfl(sl, k + g, 64);
      if (k + g < m) {
        uint4 v = x4[(size_t)s * 16 + l];
        acc[0] += bf2f((ushort_t)(v.x & 0xffff)); acc[1] += bf2f((ushort_t)(v.x >> 16));
        acc[2] += bf2f((ushort_t)(v.y & 0xffff)); acc[3] += bf2f((ushort_t)(v.y >> 16));
        acc[4] += bf2f((ushort_t)(v.z & 0xffff)); acc[5] += bf2f((ushort_t)(v.z >> 16));
        acc[6] += bf2f((ushort_t)(v.w & 0xffff)); acc[7] += bf2f((ushort_t)(v.w >> 16));
      }
    }
  }
  #pragma unroll
  for (int j = 0; j < 8; ++j) {
    acc[j] += __shfl_xor(acc[j], 16, 64);
    acc[j] += __shfl_xor(acc[j], 32, 64);
  }
  if (g == 0) {
    uint4 v = x4[(size_t)node * 16 + l];
    float di = dinv[node];
    float r0 = (acc[0] + bf2f((ushort_t)(v.x & 0xffff))) * di;
    float r1 = (acc[1] + bf2f((ushort_t)(v.x >> 16)))   * di;
    float r2 = (acc[2] + bf2f((ushort_t)(v.y & 0xffff))) * di;
    float r3 = (acc[3] + bf2f((ushort_t)(v.y >> 16)))   * di;
    float r4 = (acc[4] + bf2f((ushort_t)(v.z & 0xffff))) * di;
    float r5 = (acc[5] + bf2f((ushort_t)(v.z >> 16)))   * di;
    float r6 = (acc[6] + bf2f((ushort_t)(v.w & 0xffff))) * di;
    float r7 = (acc[7] + bf2f((ushort_t)(v.w >> 16)))   * di;
    uint4 o;
    o.x = pack2bf(r0, r1); o.y = pack2bf(r2, r3);
    o.z = pack2bf(r4, r5); o.w = pack2bf(r6, r7);
    ((uint4*)out)[(size_t)node * 16 + l] = o;
  }
}

__global__ void agg2_both_kernel(const ushort_t* __restrict__ xP, const int* __restrict__ ssrcP,
                                 const int* __restrict__ offsP, const float* __restrict__ dinvP,
                                 ushort_t* __restrict__ outP, int nP, int nblkP,
                                 const ushort_t* __restrict__ xL, const int* __restrict__ ssrcL,
                                 const int* __restrict__ offsL, const float* __restrict__ dinvL,
                                 ushort_t* __restrict__ outL, int nL) {
  int wv = threadIdx.x >> 6;
  if ((int)blockIdx.x < nblkP)
    agg128v_dev(xP, ssrcP, offsP, dinvP, outP, blockIdx.x * 4 + wv, nP);
  else
    agg128v_dev(xL, ssrcL, offsL, dinvL, outL, (blockIdx.x - nblkP) * 4 + wv, nL);
}

// ---------------- layer-2 transform via MFMA bf16 ----------------
__global__ __launch_bounds__(512) void t2_mfma_kernel(
    const ushort_t* __restrict__ aggP, const ushort_t* __restrict__ WtP,
    const float* __restrict__ bP, float* __restrict__ h2P, int nP, int nblkP,
    const ushort_t* __restrict__ aggL, const ushort_t* __restrict__ WtL,
    const float* __restrict__ bL, float* __restrict__ h2L, int nL) {
  const ushort_t* agg; const ushort_t* Wt; const float* bias; float* out; int n, n0;
  if ((int)blockIdx.x < nblkP) {
    agg = aggP; Wt = WtP; bias = bP; out = h2P; n = nP; n0 = blockIdx.x * 128;
  } else {
    agg = aggL; Wt = WtL; bias = bL; out = h2L; n = nL;
    n0 = (blockIdx.x - nblkP) * 128;
  }
  __shared__ __align__(16) short sB[16384];  // 32KB: 128 nodes x 128 k bf16
  const int t = threadIdx.x;
  const int lane = t & 63;
  const int ws = t >> 6;

  #pragma unroll
  for (int c4 = 0; c4 < 4; ++c4) {
    int cidx = t + c4 * 512;
    int node = cidx >> 4, c = cidx & 15;
    uint4 v = make_uint4(0u, 0u, 0u, 0u);
    if (n0 + node < n) v = *(const uint4*)&agg[(size_t)(n0 + node) * 128 + c * 8];
    int off16 = (((node >> 4) * 4 + (c >> 2)) * 64) + (c & 3) * 16 + (node & 15);
    *(uint4*)&sB[off16 * 8] = v;
  }

  const int fs = ws * 16;
  bf16x8 a[4];
  #pragma unroll
  for (int kc = 0; kc < 4; ++kc)
    a[kc] = *(const bf16x8*)&Wt[(size_t)(fs + (lane & 15)) * 128 + kc * 32 + (lane >> 4) * 8];

  __syncthreads();

  f32x4 acc[8];
  #pragma unroll
  for (int g = 0; g < 8; ++g) acc[g] = (f32x4){0.f, 0.f, 0.f, 0.f};

  #pragma unroll
  for (int g = 0; g < 8; ++g) {
    #pragma unroll
    for (int kc = 0; kc < 4; ++kc) {
      bf16x8 b = *(const bf16x8*)&sB[(((g * 4 + kc) * 64) + lane) * 8];
      acc[g] = __builtin_amdgcn_mfma_f32_16x16x32_bf16(a[kc], b, acc[g], 0, 0, 0);
    }
  }

  const int f0 = fs + ((lane >> 4) << 2);
  float4 bv = *(const float4*)&bias[f0];
  #pragma unroll
  for (int g = 0; g < 8; ++g) {
    int node = n0 + g * 16 + (lane & 15);
    if (node < n) {
      float4 o;
      o.x = fmaxf(acc[g][0] + bv.x, 0.f);
      o.y = fmaxf(acc[g][1] + bv.y, 0.f);
      o.z = fmaxf(acc[g][2] + bv.z, 0.f);
      o.w = fmaxf(acc[g][3] + bv.w, 0.f);
      *(float4*)&out[(size_t)node * 128 + f0] = o;
    }
  }
}

// ---------------- segmented mean-pool (both graphs) ----------------
__device__ inline void pool_dev(const float* __restrict__ h, const int* __restrict__ start,
                                float* __restrict__ mean, int g) {
  int t = threadIdx.x;
  int f = t & 127, r = t >> 7;
  int beg = start[g], end = start[g + 1];
  float acc = 0.f;
  for (int i = beg + r; i < end; i += 4)
    acc += h[(size_t)i * 128 + f];
  __shared__ float red[4][128];
  red[r][f] = acc;
  __syncthreads();
  if (r == 0) {
    float s = red[0][f] + red[1][f] + red[2][f] + red[3][f];
    float c = (float)(end - beg);
    mean[(size_t)g * 128 + f] = s / fmaxf(c, 1.f);
  }
}

__global__ __launch_bounds__(512) void pool_both_kernel(
    const float* __restrict__ hP, const int* __restrict__ startP, float* __restrict__ meanP,
    const float* __restrict__ hL, const int* __restrict__ startL, float* __restrict__ meanL,
    int G) {
  int g = blockIdx.x;
  if (g < G) pool_dev(hP, startP, meanP, g);
  else pool_dev(hL, startL, meanL, g - G);
}

// ---------------- final FC + 3 heads ----------------
__global__ __launch_bounds__(128) void fc_heads_kernel(
    const float* __restrict__ pe, const float* __restrict__ le,
    const float* __restrict__ Wfc, const float* __restrict__ bfc,
    const float* __restrict__ Wpkd, const float* __restrict__ bpkd,
    const float* __restrict__ Wpki, const float* __restrict__ bpki,
    const float* __restrict__ Wba, const float* __restrict__ bba,
    float* __restrict__ out, int G) {
  int g = blockIdx.x, f = threadIdx.x;
  __shared__ float comb[256];
  __shared__ float cbuf[128];
  comb[f]       = pe[(size_t)g * 128 + f];
  comb[128 + f] = le[(size_t)g * 128 + f];
  __syncthreads();
  float acc = bfc[f];
  for (int k = 0; k < 256; ++k) acc += comb[k] * Wfc[(size_t)k * 128 + f];
  cbuf[f] = fmaxf(acc, 0.f);
  __syncthreads();
  if (f < 64) {
    const float* Wh[3] = {Wpkd, Wpki, Wba};
    const float* bh[3] = {bpkd, bpki, bba};
    #pragma unroll
    for (int hd = 0; hd < 3; ++hd) {
      float v = cbuf[f] * Wh[hd][f] + cbuf[f + 64] * Wh[hd][f + 64];
      #pragma unroll
      for (int d = 32; d; d >>= 1) v += __shfl_xor(v, d, 64);
      if (f == 0) out[(size_t)hd * G + g] = v + bh[hd][0];
    }
  }
}

// ============================================================================
static inline size_t alignUp(size_t x, size_t a) { return (x + a - 1) / a * a; }

extern "C" void kernel_launch(void* const* d_in, const int* in_sizes, int n_in,
                              void* d_out, int out_size, void* d_ws, size_t ws_size,
                              hipStream_t stream) {
  const float* px     = (const float*)d_in[0];
  const int*   pei    = (const int*)d_in[1];
  const int*   pbatch = (const int*)d_in[2];
  const float* lx     = (const float*)d_in[3];
  const int*   lei    = (const int*)d_in[4];
  const int*   lbatch = (const int*)d_in[5];
  const float* Wp1 = (const float*)d_in[7],  *bp1 = (const float*)d_in[8];
  const float* Wp2 = (const float*)d_in[9],  *bp2 = (const float*)d_in[10];
  const float* Wl1 = (const float*)d_in[11], *bl1 = (const float*)d_in[12];
  const float* Wl2 = (const float*)d_in[13], *bl2 = (const float*)d_in[14];
  const float* Wfc = (const float*)d_in[15], *bfc = (const float*)d_in[16];
  const float* Wpkd = (const float*)d_in[17], *bpkd = (const float*)d_in[18];
  const float* Wpki = (const float*)d_in[19], *bpki = (const float*)d_in[20];
  const float* Wba  = (const float*)d_in[21], *bba  = (const float*)d_in[22];
  float* out = (float*)d_out;

  const int Np = in_sizes[0] / 23, Ep = in_sizes[1] / 2;
  const int Nl = in_sizes[3] / 4,  El = in_sizes[4] / 2;
  const int G  = out_size / 3;
  const int nb_p = (Np + SCAN_CHUNK - 1) / SCAN_CHUNK;
  const int nb_l = (Nl + SCAN_CHUNK - 1) / SCAN_CHUNK;
  const int nbk_p = (Np + (1 << BSHIFT) - 1) >> BSHIFT;   // scatter buckets
  const int nbk_l = (Nl + (1 << BSHIFT) - 1) >> BSHIFT;
  const int nbe_p = (Ep + EPB - 1) / EPB;                 // binning blocks
  const int nbe_l = (El + EPB - 1) / EPB;

  // ---- workspace layout ----
  char* base = (char*)d_ws;
  size_t off = 0;
  auto alloc = [&](size_t bytes) -> void* {
    void* p = base + off;
    off = alignUp(off + bytes, 256);
    return p;
  };
  size_t zero_beg = off;
  int*   degcnt_p = (int*)alloc((size_t)Np * 4);
  int*   cursor_p = (int*)alloc((size_t)Np * 4);
  int*   degcnt_l = (int*)alloc((size_t)Nl * 4);
  int*   cursor_l = (int*)alloc((size_t)Nl * 4);
  size_t zero_end = off;
  int*   offs_p  = (int*)alloc((size_t)(Np + 1) * 4);
  int*   offs_l  = (int*)alloc((size_t)(Nl + 1) * 4);
  int*   bsum_p  = (int*)alloc((size_t)nb_p * 4);
  int*   boffs_p = (int*)alloc((size_t)(nb_p + 1) * 4);
  int*   bsum_l  = (int*)alloc((size_t)nb_l * 4);
  int*   boffs_l = (int*)alloc((size_t)(nb_l + 1) * 4);
  int*   start_p = (int*)alloc((size_t)(G + 1) * 4);
  int*   start_l = (int*)alloc((size_t)(G + 1) * 4);
  float* dinv_p  = (float*)alloc((size_t)Np * 4);
  float* dinv_l  = (float*)alloc((size_t)Nl * 4);
  int*   ssrc_p  = (int*)alloc((size_t)Ep * 4);
  int*   ssrc_l  = (int*)alloc((size_t)El * 4);
  int2*  pair_p  = (int2*)alloc((size_t)Ep * 8);
  int2*  pair_l  = (int2*)alloc((size_t)El * 8);
  int*   cmat_p  = (int*)alloc((size_t)nbe_p * nbk_p * 4);  // [block][bucket]
  int*   cmat_l  = (int*)alloc((size_t)nbe_l * nbk_l * 4);
  float* pe_mean = (float*)alloc((size_t)G * 128 * 4);
  float* le_mean = (float*)alloc((size_t)G * 128 * 4);
  ushort_t* wt2_p = (ushort_t*)alloc((size_t)16384 * 2);
  ushort_t* wt2_l = (ushort_t*)alloc((size_t)16384 * 2);
  unsigned* xbf_p = (unsigned*)alloc((size_t)Np * 16 * 4);   // 32 bf16/row = 64B
  ushort_t* h1_p   = (ushort_t*)alloc((size_t)Np * 128 * 2);  // bf16 h1'=h1*dinv
  ushort_t* agg2_p = (ushort_t*)alloc((size_t)Np * 128 * 2);  // bf16
  float*    h2_p   = (float*)alloc((size_t)Np * 128 * 4);
  ushort_t* h1_l   = (ushort_t*)alloc((size_t)Nl * 128 * 2);  // bf16 h1'=h1*dinv
  ushort_t* agg2_l = (ushort_t*)alloc((size_t)Nl * 128 * 2);  // bf16
  float*    h2_l   = (float*)alloc((size_t)Nl * 128 * 4);
  if (off > ws_size) return;

  hipMemsetAsync(base + zero_beg, 0, zero_end - zero_beg, stream);

  const int* psrc = pei;
  const int* pdst = pei + Ep;
  const int* lsrc = lei;
  const int* ldst = lei + El;

  // ---- weight prep + protein-x bf16 conversion (independent) ----
  wprep_kernel<<<(32768 + Np * 16 + 255) / 256, 256, 0, stream>>>(
      Wp2, wt2_p, Wl2, wt2_l, px, xbf_p, Np);

  // ---- CSR build + per-node prep ----
  count_deg2_kernel<<<(Ep + El + 255) / 256, 256, 0, stream>>>(pdst, Ep, degcnt_p,
                                                               ldst, El, degcnt_l);
  node_prep_kernel<<<(Np + Nl + 255) / 256, 256, 0, stream>>>(
      degcnt_p, dinv_p, pbatch, start_p, Np,
      degcnt_l, dinv_l, lbatch, start_l, Nl, G);
  blocksum2_kernel<<<nb_p + nb_l, 256, 0, stream>>>(degcnt_p, Np, nb_p, bsum_p,
                                                    degcnt_l, Nl, bsum_l);
  exscan2_kernel<<<2, 1024, 0, stream>>>(bsum_p, boffs_p, nb_p, bsum_l, boffs_l, nb_l);
  scan_apply2_kernel<<<nb_p + nb_l, 256, 0, stream>>>(degcnt_p, boffs_p, offs_p, Np, nb_p,
                                                      degcnt_l, boffs_l, offs_l, Nl, nb_l);

  // ---- R6 binning (zero global atomics) + bucket-local scatter ----
  bin_count_kernel<<<nbe_p + nbe_l, 256, 0, stream>>>(
      pdst, Ep, nbk_p, nbe_p, cmat_p,
      ldst, El, nbk_l, cmat_l);
  bin_scan_kernel<<<nbk_p + nbk_l, 256, 0, stream>>>(
      offs_p, nbk_p, nbe_p, cmat_p,
      offs_l, nbk_l, nbe_l, cmat_l);
  bin_place_kernel<<<nbe_p + nbe_l, 256, 0, stream>>>(
      psrc, pdst, Ep, nbk_p, nbe_p, cmat_p, pair_p,
      lsrc, ldst, El, nbk_l, cmat_l, pair_l);
  bucket_pass2_kernel<<<nbk_p + nbk_l, 256, 0, stream>>>(
      pair_p, offs_p, cursor_p, ssrc_p, Np, nbk_p,
      pair_l, offs_l, cursor_l, ssrc_l, Nl);

  // ---- GNN layer 1: fused aggregate+transform (R7/R8) ----
  const int a1blkP = (Np + 15) / 16, a1blkL = (Nl + 15) / 16;
  agg1t_both_kernel<<<a1blkP + a1blkL, 256, 0, stream>>>(
      xbf_p, ssrc_p, offs_p, dinv_p, Wp1, bp1, h1_p, Np, a1blkP,
      lx, ssrc_l, offs_l, dinv_l, Wl1, bl1, h1_l, Nl);

  // ---- GNN layer 2 (both graphs fused) ----
  const int ablkP = (Np + 3) / 4, ablkL = (Nl + 3) / 4;
  agg2_both_kernel<<<ablkP + ablkL, 256, 0, stream>>>(
      h1_p, ssrc_p, offs_p, dinv_p, agg2_p, Np, ablkP,
      h1_l, ssrc_l, offs_l, dinv_l, agg2_l, Nl);
  const int mblkP = (Np + 127) / 128, mblkL = (Nl + 127) / 128;
  t2_mfma_kernel<<<mblkP + mblkL, 512, 0, stream>>>(
      agg2_p, wt2_p, bp2, h2_p, Np, mblkP,
      agg2_l, wt2_l, bl2, h2_l, Nl);

  // ---- pool + FC/heads ----
  pool_both_kernel<<<2 * G, 512, 0, stream>>>(h2_p, start_p, pe_mean,
                                              h2_l, start_l, le_mean, G);
  fc_heads_kernel<<<G, 128, 0, stream>>>(pe_mean, le_mean, Wfc, bfc,
                                         Wpkd, bpkd, Wpki, bpki, Wba, bba, out, G);
}